// Round 14
// baseline (341.893 us; speedup 1.0000x reference)
//
#include <hip/hip_runtime.h>

typedef __attribute__((ext_vector_type(8))) short bf16x8;
typedef __attribute__((ext_vector_type(4))) short s16x4;
typedef __attribute__((ext_vector_type(4))) float f32x4;
typedef unsigned int u32;

#define SQ 1024
#define BB 8
#define DM 512
#define NH 8
#define HD 64
#define FF 2048
#define NROWS (SQ*BB)

static __device__ __forceinline__ float b2f(short s) {
  return __uint_as_float(((u32)(unsigned short)s) << 16);
}
static __device__ __forceinline__ short f2b(float f) {
  u32 u = __float_as_uint(f);
  return (short)((u + 0x7FFFu + ((u >> 16) & 1u)) >> 16);
}
// cheap round (non-RNE) for hot inner-loop LDS stores
static __device__ __forceinline__ short f2bt(float f) {
  return (short)((__float_as_uint(f) + 0x8000u) >> 16);
}
static __device__ __forceinline__ float sigm(float x) { return 1.f / (1.f + __expf(-x)); }

static __device__ __forceinline__ f32x4 mfma16(bf16x8 a, bf16x8 b, f32x4 c) {
  return __builtin_amdgcn_mfma_f32_16x16x32_bf16(a, b, c, 0, 0, 0);
}

static __device__ __forceinline__ void gload16(const void* g, void* l) {
  __builtin_amdgcn_global_load_lds(
      (const __attribute__((address_space(1))) void*)g,
      (__attribute__((address_space(3))) void*)l, 16, 0, 0);
}

// XOR swizzle for row-major [*][64 bf16] tiles (128 B row stride)
static __device__ __forceinline__ int swzp(int r, int byteoff) {
  return (r * 128 + byteoff) ^ ((r & 7) << 4);
}

#define WAIT_LGKM() do { \
    asm volatile("s_waitcnt lgkmcnt(0)" ::: "memory"); \
    __builtin_amdgcn_sched_barrier(0); } while (0)
#define WAIT_VM(n) do { \
    asm volatile("s_waitcnt vmcnt(" #n ")" ::: "memory"); \
    __builtin_amdgcn_sched_barrier(0); } while (0)

// ---------------- batched f32 -> bf16 convert (10 segments, 1 launch) ----------------
struct CvtArgs {
  const float* s[10];
  short* d[10];
  int n4[10];
  int cum[10];
};
__global__ __launch_bounds__(256) void cvt_multi(CvtArgs a) {
  int bid = blockIdx.x;
  int seg = 0;
#pragma unroll
  for (int i = 1; i < 10; ++i) if (bid >= a.cum[i]) seg = i;
  int idx = (bid - a.cum[seg]) * 256 + threadIdx.x;
  if (idx >= a.n4[seg]) return;
  float4 v = ((const float4*)a.s[seg])[idx];
  s16x4 r = { f2b(v.x), f2b(v.y), f2b(v.z), f2b(v.w) };
  ((s16x4*)a.d[seg])[idx] = r;
}

// ---------------- row LayerNorm, D=512, one wave per row ----------------
// MODE 0: bf16 out; 1: f32 out.  INF32: input dtype.
template<int MODE, int INF32>
__global__ __launch_bounds__(256) void ln_kernel(const void* __restrict__ xin,
                                                 const float* __restrict__ gam,
                                                 const float* __restrict__ bet,
                                                 void* __restrict__ out) {
  int w = threadIdx.x >> 6, lane = threadIdx.x & 63;
  int row = (blockIdx.x << 2) + w;
  float v[8];
  if (INF32) {
    const float* xr = (const float*)xin + (size_t)row * DM + lane * 8;
    float4 a = *(const float4*)xr;
    float4 c = *(const float4*)(xr + 4);
    v[0]=a.x; v[1]=a.y; v[2]=a.z; v[3]=a.w; v[4]=c.x; v[5]=c.y; v[6]=c.z; v[7]=c.w;
  } else {
    bf16x8 x8 = *(const bf16x8*)((const short*)xin + (size_t)row * DM + lane * 8);
#pragma unroll
    for (int e = 0; e < 8; ++e) v[e] = b2f(x8[e]);
  }
  float s = 0.f, q = 0.f;
#pragma unroll
  for (int e = 0; e < 8; ++e) { s += v[e]; q += v[e] * v[e]; }
#pragma unroll
  for (int m = 1; m < 64; m <<= 1) { s += __shfl_xor(s, m); q += __shfl_xor(q, m); }
  float mean = s * (1.f / DM);
  float rstd = rsqrtf(q * (1.f / DM) - mean * mean + 1e-5f);
  int col = lane * 8;
  if (MODE == 1) {
    float* o = (float*)out + (size_t)row * DM + col;
    float y[8];
#pragma unroll
    for (int e = 0; e < 8; ++e) y[e] = (v[e] - mean) * rstd * gam[col + e] + bet[col + e];
    *(float4*)o = make_float4(y[0], y[1], y[2], y[3]);
    *(float4*)(o + 4) = make_float4(y[4], y[5], y[6], y[7]);
  } else {
    bf16x8 r;
#pragma unroll
    for (int e = 0; e < 8; ++e) {
      float y = (v[e] - mean) * rstd * gam[col + e] + bet[col + e];
      r[e] = f2b(y);
    }
    *(bf16x8*)((short*)out + (size_t)row * DM + col) = r;
  }
}

// ---------------- 256x256 GEMM, BK=32, ring-3, counted vmcnt, st_16x32 swizzle ----------------
template<int EPI>
__global__ __launch_bounds__(512, 2) void gemm256(const short* __restrict__ A,
                                                  const short* __restrict__ W,
                                                  const float* __restrict__ bias,
                                                  short* __restrict__ out,
                                                  int M, int N, int K) {
  __shared__ __align__(16) short lds[3 * 16384];
  int nb = N >> 8;
  int nwg = gridDim.x, bid = blockIdx.x;
  int bid2 = ((nwg & 7) == 0) ? ((bid & 7) * (nwg >> 3) + (bid >> 3)) : bid;
  int bm = bid2 / nb, bn = bid2 % nb;
  int m0 = bm << 8, n0 = bn << 8;
  int tid = threadIdx.x, w = tid >> 6, lane = tid & 63;
  int wm = w >> 2, wn = w & 3;
  int l15 = lane & 15, l4 = lane >> 4;
  int srow = lane >> 2;
  int slog = (lane & 3) ^ (((lane >> 5) & 1) << 1);
  int scol = slog << 3;

  const short* gsrc = (w < 4) ? (A + (size_t)(m0 + w * 64 + srow) * K + scol)
                              : (W + (size_t)(n0 + (w - 4) * 64 + srow) * K + scol);

  f32x4 acc[8][4];
#pragma unroll
  for (int i = 0; i < 8; ++i)
#pragma unroll
    for (int j = 0; j < 4; ++j) acc[i][j] = (f32x4){0.f, 0.f, 0.f, 0.f};

  auto stage2 = [&](int u, int kt, int q0) {
#pragma unroll
    for (int q = q0; q < q0 + 2; ++q)
      gload16(gsrc + (size_t)(q * 16) * K + kt,
              (char*)lds + u * 32768 + (w * 4 + q) * 1024);
  };
  auto rdA = [&](int u, int mf) -> bf16x8 {
    int ps = l4 ^ (((l15 >> 3) & 1) << 1);
    return *(const bf16x8*)((char*)lds + u * 32768 + (wm * 8 + mf) * 1024 + l15 * 64 + ps * 16);
  };
  auto rdB = [&](int u, int nf) -> bf16x8 {
    int ps = l4 ^ (((l15 >> 3) & 1) << 1);
    return *(const bf16x8*)((char*)lds + u * 32768 + 16384 + (wn * 4 + nf) * 1024 + l15 * 64 + ps * 16);
  };

  int nt = K >> 5;
  stage2(0, 0, 0); stage2(0, 0, 2);
  stage2(1, 32, 0); stage2(1, 32, 2);
  WAIT_VM(4);
  __builtin_amdgcn_s_barrier();

  int u = 0;
  for (int t = 0; t < nt; ++t) {
    int kt2 = (t + 2) << 5;
    int us = u + 2; if (us >= 3) us -= 3;
    bool st = (t + 2) < nt;
    bf16x8 afrag[4], bfrag[4];
#pragma unroll
    for (int nf = 0; nf < 4; ++nf) bfrag[nf] = rdB(u, nf);
#pragma unroll
    for (int mf = 0; mf < 4; ++mf) afrag[mf] = rdA(u, mf);
    if (st) stage2(us, kt2, 0);
    __builtin_amdgcn_s_barrier();
    WAIT_LGKM();
    __builtin_amdgcn_s_setprio(1);
#pragma unroll
    for (int mf = 0; mf < 4; ++mf)
#pragma unroll
      for (int nf = 0; nf < 4; ++nf)
        acc[mf][nf] = mfma16(afrag[mf], bfrag[nf], acc[mf][nf]);
    __builtin_amdgcn_s_setprio(0);
    __builtin_amdgcn_s_barrier();
#pragma unroll
    for (int mf = 0; mf < 4; ++mf) afrag[mf] = rdA(u, mf + 4);
    if (st) stage2(us, kt2, 2);
    __builtin_amdgcn_s_barrier();
    WAIT_LGKM();
    __builtin_amdgcn_s_setprio(1);
#pragma unroll
    for (int mf = 0; mf < 4; ++mf)
#pragma unroll
      for (int nf = 0; nf < 4; ++nf)
        acc[mf + 4][nf] = mfma16(afrag[mf], bfrag[nf], acc[mf + 4][nf]);
    __builtin_amdgcn_s_setprio(0);
    if (t < nt - 1) {
      if (st) { WAIT_VM(4); } else { WAIT_VM(0); }
    }
    __builtin_amdgcn_s_barrier();
    ++u; if (u >= 3) u -= 3;
  }

#pragma unroll
  for (int nf = 0; nf < 4; ++nf) {
    int col = n0 + wn * 64 + nf * 16 + l15;
    float bv = bias[col];
#pragma unroll
    for (int mf = 0; mf < 8; ++mf) {
#pragma unroll
      for (int r4 = 0; r4 < 4; ++r4) {
        int row = m0 + wm * 128 + mf * 16 + l4 * 4 + r4;
        float v = acc[mf][nf][r4] + bv;
        if (EPI == 1) v = v * sigm(v);
        out[(size_t)row * N + col] = f2b(v);
      }
    }
  }
}

// ---------------- 128x128 GEMM: ring-3, counted vmcnt, 1 barrier/iter ----------------
// EPI 0: +bias -> bf16 ; 1: swish(+bias) -> bf16 ; 2: res + alpha*(acc+bias) -> bf16 ;
// 3: plain -> bf16.  RESF32: residual dtype.
template<int EPI, int RESF32>
__global__ __launch_bounds__(256, 3) void gemm128(const short* __restrict__ A,
                                                  const short* __restrict__ W,
                                                  const float* __restrict__ bias,
                                                  const void* __restrict__ res,
                                                  float alpha, short* __restrict__ out,
                                                  int M, int N, int K) {
  __shared__ __align__(16) short lds[3 * 8192];
  int nb = N >> 7;
  int nwg = gridDim.x, bid = blockIdx.x;
  int bid2 = ((nwg & 7) == 0) ? ((bid & 7) * (nwg >> 3) + (bid >> 3)) : bid;
  int bm = bid2 / nb, bn = bid2 % nb;
  int m0 = bm << 7, n0 = bn << 7;
  int tid = threadIdx.x, w = tid >> 6, lane = tid & 63;
  int wm = w >> 1, wn = w & 1;
  int l15 = lane & 15, l4 = lane >> 4;
  int srow = lane >> 2;
  int slog = (lane & 3) ^ (((lane >> 5) & 1) << 1);
  int scol = slog << 3;

  const short* gsrc = (w < 2) ? (A + (size_t)(m0 + w * 64 + srow) * K + scol)
                              : (W + (size_t)(n0 + (w - 2) * 64 + srow) * K + scol);
  int ldsbase = w * 4096;

  f32x4 acc[4][4];
#pragma unroll
  for (int i = 0; i < 4; ++i)
#pragma unroll
    for (int j = 0; j < 4; ++j) acc[i][j] = (f32x4){0.f, 0.f, 0.f, 0.f};

  auto stage = [&](int u, int kt) {
#pragma unroll
    for (int q = 0; q < 4; ++q)
      gload16(gsrc + (size_t)(q * 16) * K + kt,
              (char*)lds + u * 16384 + ldsbase + q * 1024);
  };
  auto rdA = [&](int u, int mf) -> bf16x8 {
    int ps = l4 ^ (((l15 >> 3) & 1) << 1);
    return *(const bf16x8*)((char*)lds + u * 16384 + (wm * 4 + mf) * 1024 + l15 * 64 + ps * 16);
  };
  auto rdB = [&](int u, int nf) -> bf16x8 {
    int ps = l4 ^ (((l15 >> 3) & 1) << 1);
    return *(const bf16x8*)((char*)lds + u * 16384 + 8192 + (wn * 4 + nf) * 1024 + l15 * 64 + ps * 16);
  };

  int nt = K >> 5;
  stage(0, 0);
  stage(1, 32);
  WAIT_VM(4);
  __builtin_amdgcn_s_barrier();

  int u = 0;
  for (int t = 0; t < nt; ++t) {
    int us = u + 2; if (us >= 3) us -= 3;
    bool st = (t + 2) < nt;
    bf16x8 afrag[4], bfrag[4];
#pragma unroll
    for (int mf = 0; mf < 4; ++mf) afrag[mf] = rdA(u, mf);
#pragma unroll
    for (int nf = 0; nf < 4; ++nf) bfrag[nf] = rdB(u, nf);
    if (st) stage(us, (t + 2) << 5);
    WAIT_LGKM();
    __builtin_amdgcn_s_setprio(1);
#pragma unroll
    for (int mf = 0; mf < 4; ++mf)
#pragma unroll
      for (int nf = 0; nf < 4; ++nf)
        acc[mf][nf] = mfma16(afrag[mf], bfrag[nf], acc[mf][nf]);
    __builtin_amdgcn_s_setprio(0);
    if (t < nt - 1) {
      if (st) { WAIT_VM(4); } else { WAIT_VM(0); }
    }
    __builtin_amdgcn_s_barrier();
    ++u; if (u >= 3) u -= 3;
  }

#pragma unroll
  for (int mf = 0; mf < 4; ++mf) {
#pragma unroll
    for (int nf = 0; nf < 4; ++nf) {
      int col = n0 + wn * 64 + nf * 16 + l15;
      float bv = (EPI == 3) ? 0.f : bias[col];
#pragma unroll
      for (int r4 = 0; r4 < 4; ++r4) {
        int row = m0 + wm * 64 + mf * 16 + l4 * 4 + r4;
        size_t idx = (size_t)row * N + col;
        float v = acc[mf][nf][r4] + bv;
        if (EPI == 0 || EPI == 3) {
          out[idx] = f2b(v);
        } else if (EPI == 1) {
          out[idx] = f2b(v * sigm(v));
        } else {
          float rv = RESF32 ? ((const float*)res)[idx] : b2f(((const short*)res)[idx]);
          out[idx] = f2b(rv + alpha * v);
        }
      }
    }
  }
}

// ---------------- V-transpose prep: qkv V section -> VT [bh][d][s] ----------------
__global__ __launch_bounds__(256) void prep_kernel(const short* __restrict__ qkv,
                                                   short* __restrict__ VTp) {
  __shared__ short ldsv[64 * 66];
  int tid = threadIdx.x;
  int st = blockIdx.x & 15, bh = blockIdx.x >> 4;
  int b = bh >> 3, h = bh & 7;
  int s0 = st << 6;
#pragma unroll
  for (int pass = 0; pass < 2; ++pass) {
    int r = pass * 32 + (tid >> 3), c = tid & 7;
    int s = s0 + r;
    bf16x8 v8 = *(const bf16x8*)(qkv + (size_t)(s * BB + b) * 1536 + 1024 + h * 64 + c * 8);
    *(bf16x8*)(ldsv + r * 66 + c * 8) = v8;
  }
  __syncthreads();
#pragma unroll
  for (int pass = 0; pass < 2; ++pass) {
    int d = pass * 32 + (tid >> 3), sc = tid & 7;
    bf16x8 o;
#pragma unroll
    for (int u = 0; u < 8; ++u) o[u] = ldsv[(sc * 8 + u) * 66 + d];
    *(bf16x8*)(VTp + ((size_t)bh * 64 + d) * SQ + s0 + sc * 8) = o;
  }
}

// ---------------- fused rel-pos flash attention ----------------
// grid = 8(it) * 64(bh) [XCD-local]; block 512 (8 waves)
__global__ __launch_bounds__(512, 4) void attn_kernel(const short* __restrict__ qkv,
                                                      const short* __restrict__ VTp,
                                                      const short* __restrict__ posb,
                                                      const float* __restrict__ bias_u,
                                                      const float* __restrict__ bias_v,
                                                      short* __restrict__ obuf) {
  __shared__ __align__(16) char smem[78848];
  char* lds_k   = smem;            // 2 x [64][64] bf16 swizzled (16KB)
  char* lds_vt  = smem + 16384;    // [64 d][64 j] (8KB)
  char* lds_pos = smem + 24576;    // 4 segs x [64][64] (32KB), circular
  char* lds_ew  = smem + 57344;    // 8 waves x 2688B; e band [16 q][84 n]; P overlaps

  int tid = threadIdx.x, w = tid >> 6, lane = tid & 63;
  int l15 = lane & 15, l4 = lane >> 4;
  int it = blockIdx.x >> 6, bh = blockIdx.x & 63;
  int b = bh >> 3, h = bh & 7;
  int i0 = it << 7;
  char* ewb = lds_ew + w * 2688;

  const size_t hoffB = (size_t)bh * SQ * 128;

  const float SC2 = 0.125f * 1.44269504f;
  int fr = i0 + w * 16 + l15;
  const short* qrow = qkv + (size_t)(fr * BB + b) * 1536 + h * 64;
  bf16x8 qu_f[2], qv_f[2];
#pragma unroll
  for (int ks = 0; ks < 2; ++ks) {
    bf16x8 qraw = *(const bf16x8*)(qrow + ks * 32 + l4 * 8);
#pragma unroll
    for (int e = 0; e < 8; ++e) {
      float qf = b2f(qraw[e]);
      int d = h * 64 + ks * 32 + l4 * 8 + e;
      qu_f[ks][e] = f2b((qf + bias_u[d]) * SC2);
      qv_f[ks][e] = f2b((qf + bias_v[d]) * SC2);
    }
  }

  float m_run = -1e30f, l_run = 0.f;
  f32x4 o_acc[4];
#pragma unroll
  for (int dt = 0; dt < 4; ++dt) o_acc[dt] = (f32x4){0.f, 0.f, 0.f, 0.f};

  int prbase = 112 - 16 * w;
  int lnq = lane >> 3, lnr = lane & 7;
  int r8 = w * 8 + lnq;
  int byt = (lnr * 16) ^ ((r8 & 7) << 4);
  int nbase = 896 - i0;

  auto stageK = [&](int t1) {
    int j = (t1 << 6) + r8;
    gload16((const char*)qkv + (size_t)(j * BB + b) * 3072 + 1024 + h * 128 + byt,
            lds_k + (t1 & 1) * 8192 + w * 1024);
  };
  auto stageVT = [&](int t1) {
    gload16((const char*)VTp + hoffB + (size_t)r8 * 2048 + (size_t)(t1 << 7) + byt,
            lds_vt + w * 1024);
  };
  auto stagePosSeg = [&](int gbase, int pseg) {
    gload16((const char*)posb + (size_t)(gbase + r8) * 1024 + h * 128 + byt,
            lds_pos + pseg * 8192 + w * 1024);
  };

  stagePosSeg(nbase, 0);
  stagePosSeg(nbase + 64, 1);
  stagePosSeg(nbase + 128, 2);
  stageK(0);
  WAIT_VM(0);

  for (int t = 0; t < 16; ++t) {
    int cur = t & 1;
    __builtin_amdgcn_s_barrier();
    stageVT(t);

    f32x4 acs[4];
    __builtin_amdgcn_s_setprio(1);
#pragma unroll
    for (int kt = 0; kt < 4; ++kt) {
      f32x4 z = (f32x4){0.f, 0.f, 0.f, 0.f};
      bf16x8 kb0 = *(const bf16x8*)(lds_k + cur * 8192 + swzp(kt * 16 + l15, l4 * 16));
      bf16x8 kb1 = *(const bf16x8*)(lds_k + cur * 8192 + swzp(kt * 16 + l15, 64 + l4 * 16));
      z = mfma16(kb0, qu_f[0], z);
      z = mfma16(kb1, qu_f[1], z);
      acs[kt] = z;
    }
    __builtin_amdgcn_s_setprio(0);
#pragma unroll
    for (int pt = 0; pt < 5; ++pt) {
      f32x4 z = (f32x4){0.f, 0.f, 0.f, 0.f};
      int pr = prbase + pt * 16 + l15;
      char* pbase = lds_pos + (((t + (pr >> 6)) & 3) * 8192);
      bf16x8 pb0 = *(const bf16x8*)(pbase + swzp(pr & 63, l4 * 16));
      bf16x8 pb1 = *(const bf16x8*)(pbase + swzp(pr & 63, 64 + l4 * 16));
      __builtin_amdgcn_s_setprio(1);
      z = mfma16(pb0, qv_f[0], z);
      z = mfma16(pb1, qv_f[1], z);
      __builtin_amdgcn_s_setprio(0);
      s16x4 ek;
#pragma unroll
      for (int r = 0; r < 4; ++r) ek[r] = f2bt(z[r]);
      *(s16x4*)(ewb + (l15 * 84 + pt * 16 + l4 * 4) * 2) = ek;
    }

    bool pf = (t + 1) < 16;
    if (pf) {
      stageK(t + 1);
      stagePosSeg(nbase + (t << 6) + 192, (t + 3) & 3);
    }

    WAIT_LGKM();

    float sv[4][4];
#pragma unroll
    for (int kt = 0; kt < 4; ++kt) {
#pragma unroll
      for (int r = 0; r < 4; ++r) {
        int n = 15 - l15 + kt * 16 + l4 * 4 + r;
        float ev = b2f(*(const short*)(ewb + (l15 * 84 + n) * 2));
        sv[kt][r] = acs[kt][r] + ev;
      }
    }
    float mk[4];
#pragma unroll
    for (int kt = 0; kt < 4; ++kt)
      mk[kt] = fmaxf(fmaxf(sv[kt][0], sv[kt][1]), fmaxf(sv[kt][2], sv[kt][3]));
    float mt = fmaxf(fmaxf(mk[0], mk[1]), fmaxf(mk[2], mk[3]));

    if (!__all(mt <= m_run + 11.5415604f)) {
      float mr = fmaxf(mt, __shfl_xor(mt, 16));
      mr = fmaxf(mr, __shfl_xor(mr, 32));
      float mn = fmaxf(m_run, mr);
      float fac = exp2f(m_run - mn);
      m_run = mn;
      l_run *= fac;
      float fb[4];
#pragma unroll
      for (int r4 = 0; r4 < 4; ++r4) fb[r4] = __shfl(fac, (l4 << 2) + r4);
#pragma unroll
      for (int dt = 0; dt < 4; ++dt)
#pragma unroll
        for (int r4 = 0; r4 < 4; ++r4) o_acc[dt][r4] *= fb[r4];
    }
    float lsk[4];
#pragma unroll
    for (int kt = 0; kt < 4; ++kt) {
      s16x4 pk;
      float p[4];
#pragma unroll
      for (int r = 0; r < 4; ++r) {
        p[r] = exp2f(sv[kt][r] - m_run);
        pk[r] = f2bt(p[r]);
      }
      lsk[kt] = (p[0] + p[1]) + (p[2] + p[3]);
      *(s16x4*)(ewb + l15 * 128 + ((kt * 32 + l4 * 8) ^ ((l15 & 7) << 4))) = pk;
    }
    l_run += (lsk[0] + lsk[1]) + (lsk[2] + lsk[3]);

    if (pf) { WAIT_VM(2); } else { WAIT_VM(0); }
    WAIT_LGKM();
    __builtin_amdgcn_s_barrier();

    bf16x8 pa[2];
#pragma unroll
    for (int ks = 0; ks < 2; ++ks)
      pa[ks] = *(const bf16x8*)(ewb + swzp(l15, ks * 64 + l4 * 16));
    __builtin_amdgcn_s_setprio(1);
#pragma unroll
    for (int dt = 0; dt < 4; ++dt) {
      bf16x8 vb0 = *(const bf16x8*)(lds_vt + swzp(dt * 16 + l15, l4 * 16));
      bf16x8 vb1 = *(const bf16x8*)(lds_vt + swzp(dt * 16 + l15, 64 + l4 * 16));
      o_acc[dt] = mfma16(pa[0], vb0, o_acc[dt]);
      o_acc[dt] = mfma16(pa[1], vb1, o_acc[dt]);
    }
    __builtin_amdgcn_s_setprio(0);

    WAIT_VM(0);
  }

  float lt = l_run + __shfl_xor(l_run, 16);
  lt += __shfl_xor(lt, 32);
  float lb[4];
#pragma unroll
  for (int r4 = 0; r4 < 4; ++r4) lb[r4] = __shfl(lt, (l4 << 2) + r4);
#pragma unroll
  for (int dt = 0; dt < 4; ++dt) {
#pragma unroll
    for (int r4 = 0; r4 < 4; ++r4) {
      int i = i0 + w * 16 + l4 * 4 + r4;
      int d = dt * 16 + l15;
      float val = o_acc[dt][r4] / lb[r4];
      obuf[(size_t)(i * BB + b) * DM + h * 64 + d] = f2b(val);
    }
  }
}

// ---------------- GLU + depthwise conv (K=31) + fused LayerNorm + swish -> bf16 ----------------
// Register sliding-window FIR: depthwise conv has NO cross-channel sharing, so no
// data-LDS. Each thread owns channel d (and d+256): loads its own 38-row (a,g)
// window direct from global (lanes = consecutive channels -> coalesced), GLU in
// f32, 31-tap FIR from v[38] registers. LDS only for the LN cross-wave reduce.
__global__ __launch_bounds__(256) void glu_dwconv_kernel(const short* __restrict__ pw1,
                                                         const float* __restrict__ dww,
                                                         const float* __restrict__ dwb,
                                                         const float* __restrict__ cg,
                                                         const float* __restrict__ cb,
                                                         short* __restrict__ outbf) {
  __shared__ float red[8][4][2];
  int tid = threadIdx.x;
  int b = blockIdx.x & 7;
  int s0 = (blockIdx.x >> 3) << 3;

  float a0[8], a1[8];
#pragma unroll
  for (int half = 0; half < 2; ++half) {
    int d = tid + half * 256;
    float v[38];
#pragma unroll
    for (int r = 0; r < 38; ++r) {
      int s = s0 - 15 + r;
      float gl = 0.f;
      if (s >= 0 && s < SQ) {
        const short* row = pw1 + (size_t)(s * BB + b) * 1024;
        float av = b2f(row[d]);
        float gv = b2f(row[512 + d]);
        gl = av * sigm(gv);
      }
      v[r] = gl;
    }
    float wreg[31];
#pragma unroll
    for (int k = 0; k < 31; ++k) wreg[k] = dww[d * 31 + k];
    float bb = dwb[d];
#pragma unroll
    for (int ri = 0; ri < 8; ++ri) {
      float acc = bb;
#pragma unroll
      for (int k = 0; k < 31; ++k) acc += wreg[k] * v[ri + k];
      if (half == 0) a0[ri] = acc; else a1[ri] = acc;
    }
  }

  // fused LayerNorm over 512 channels per row + swish
  int w = tid >> 6, lane = tid & 63;
#pragma unroll
  for (int ri = 0; ri < 8; ++ri) {
    float sp = a0[ri] + a1[ri];
    float qp = a0[ri] * a0[ri] + a1[ri] * a1[ri];
#pragma unroll
    for (int m = 1; m < 64; m <<= 1) { sp += __shfl_xor(sp, m); qp += __shfl_xor(qp, m); }
    if (lane == 0) { red[ri][w][0] = sp; red[ri][w][1] = qp; }
  }
  __syncthreads();
  float g0 = cg[tid], b0 = cb[tid], g1 = cg[tid + 256], b1 = cb[tid + 256];
#pragma unroll
  for (int ri = 0; ri < 8; ++ri) {
    float s = red[ri][0][0] + red[ri][1][0] + red[ri][2][0] + red[ri][3][0];
    float q = red[ri][0][1] + red[ri][1][1] + red[ri][2][1] + red[ri][3][1];
    float mean = s * (1.f / DM);
    float rstd = rsqrtf(q * (1.f / DM) - mean * mean + 1e-5f);
    float y0 = (a0[ri] - mean) * rstd * g0 + b0;
    float y1 = (a1[ri] - mean) * rstd * g1 + b1;
    y0 = y0 * sigm(y0);
    y1 = y1 * sigm(y1);
    size_t base = (size_t)((s0 + ri) * BB + b) * 512;
    outbf[base + tid] = f2b(y0);
    outbf[base + tid + 256] = f2b(y1);
  }
}

// ---------------- host ----------------
extern "C" void kernel_launch(void* const* d_in, const int* in_sizes, int n_in,
                              void* d_out, int out_size, void* d_ws, size_t ws_size,
                              hipStream_t stream) {
  const float* src    = (const float*)d_in[0];
  const float* pose   = (const float*)d_in[1];
  const float* ffm_w1 = (const float*)d_in[2];
  const float* ffm_b1 = (const float*)d_in[3];
  const float* ffm_w2 = (const float*)d_in[4];
  const float* ffm_b2 = (const float*)d_in[5];
  const float* in_w   = (const float*)d_in[6];
  const float* in_b   = (const float*)d_in[7];
  const float* out_w  = (const float*)d_in[8];
  const float* out_b  = (const float*)d_in[9];
  const float* pos_w  = (const float*)d_in[10];
  const float* bias_u = (const float*)d_in[11];
  const float* bias_v = (const float*)d_in[12];
  const float* pw1_w  = (const float*)d_in[13];
  const float* pw1_b  = (const float*)d_in[14];
  const float* dw_w   = (const float*)d_in[15];
  const float* dw_b   = (const float*)d_in[16];
  const float* cng    = (const float*)d_in[17];
  const float* cnb    = (const float*)d_in[18];
  const float* pw2_w  = (const float*)d_in[19];
  const float* pw2_b  = (const float*)d_in[20];
  const float* ff_w1  = (const float*)d_in[21];
  const float* ff_b1  = (const float*)d_in[22];
  const float* ff_w2  = (const float*)d_in[23];
  const float* ff_b2  = (const float*)d_in[24];
  const float* g_ffm  = (const float*)d_in[25];
  const float* b_ffm  = (const float*)d_in[26];
  const float* g_mha  = (const float*)d_in[27];
  const float* b_mha  = (const float*)d_in[28];
  const float* g_conv = (const float*)d_in[29];
  const float* b_conv = (const float*)d_in[30];
  const float* g_ff   = (const float*)d_in[31];
  const float* b_ff   = (const float*)d_in[32];
  const float* g_fin  = (const float*)d_in[33];
  const float* b_fin  = (const float*)d_in[34];

  char* ws = (char*)d_ws;
  size_t off = 0;
  auto alloc = [&](size_t bytes) -> void* {
    void* p = ws + off;
    off += (bytes + 255) & ~(size_t)255;
    return p;
  };
  short* wb_ffm1 = (short*)alloc((size_t)FF * DM * 2);
  short* wb_ffm2 = (short*)alloc((size_t)DM * FF * 2);
  short* wb_in   = (short*)alloc((size_t)3 * DM * DM * 2);
  short* wb_out  = (short*)alloc((size_t)DM * DM * 2);
  short* wb_pos  = (short*)alloc((size_t)DM * DM * 2);
  short* wb_pw1  = (short*)alloc((size_t)2 * DM * DM * 2);
  short* wb_pw2  = (short*)alloc((size_t)DM * DM * 2);
  short* wb_ff1  = (short*)alloc((size_t)FF * DM * 2);
  short* wb_ff2  = (short*)alloc((size_t)DM * FF * 2);
  short* pos_src = (short*)alloc((size_t)2048 * DM * 2);
  short* pos_bf  = (short*)alloc((size_t)2048 * DM * 2);
  short* lnb     = (short*)alloc((size_t)NROWS * DM * 2);
  short* hbig    = (short*)alloc((size_t)NROWS * FF * 2);
  short* qkvb    = (short*)alloc((size_t)NROWS * 3 * DM * 2);
  short* obuf    = (short*)alloc((size_t)NROWS * DM * 2);
  short* x1      = (short*)alloc((size_t)NROWS * DM * 2);
  short* x2      = (short*)alloc((size_t)NROWS * DM * 2);
  short* pw1raw  = hbig;
  short* convy   = obuf;
  short* x3 = x1;
  short* x4 = x2;
  short* VTp = hbig + (size_t)3 * 4194304;

  CvtArgs ca;
  const float* srcs[10] = {ffm_w1, ffm_w2, in_w, out_w, pos_w, pw1_w, pw2_w, ff_w1, ff_w2, pose};
  short* dsts[10] = {wb_ffm1, wb_ffm2, wb_in, wb_out, wb_pos, wb_pw1, wb_pw2, wb_ff1, wb_ff2, pos_src};
  size_t ns[10] = {(size_t)FF*DM, (size_t)DM*FF, (size_t)3*DM*DM, (size_t)DM*DM, (size_t)DM*DM,
                   (size_t)2*DM*DM, (size_t)DM*DM, (size_t)FF*DM, (size_t)DM*FF, (size_t)2047*DM};
  int cum = 0;
  for (int i = 0; i < 10; ++i) {
    ca.s[i] = srcs[i]; ca.d[i] = dsts[i];
    ca.n4[i] = (int)(ns[i] >> 2);
    ca.cum[i] = cum;
    cum += (ca.n4[i] + 255) / 256;
  }
  cvt_multi<<<dim3(cum), dim3(256), 0, stream>>>(ca);

  auto gemmR = [&](int RESF32, const short* A, const short* W, const float* bias,
                   const void* res, float alpha, short* out, int M, int N, int K) {
    dim3 g((M / 128) * (N / 128)), blk(256);
    if (RESF32) gemm128<2, 1><<<g, blk, 0, stream>>>(A, W, bias, res, alpha, out, M, N, K);
    else        gemm128<2, 0><<<g, blk, 0, stream>>>(A, W, bias, res, alpha, out, M, N, K);
  };
  auto gemm2 = [&](int EPI, const short* A, const short* W, const float* bias,
                   short* out, int M, int N, int K) {
    dim3 g((M / 256) * (N / 256)), blk(512);
    if (EPI == 0) gemm256<0><<<g, blk, 0, stream>>>(A, W, bias, out, M, N, K);
    else          gemm256<1><<<g, blk, 0, stream>>>(A, W, bias, out, M, N, K);
  };

  // positional projection (plain bf16 out): 2048x512x512
  gemm128<3, 0><<<dim3((2048 / 128) * (512 / 128)), dim3(256), 0, stream>>>(
      pos_src, wb_pos, nullptr, nullptr, 0.f, pos_bf, 2048, DM, DM);

  // macaron FFN: x1 = src + 0.5*ffn(ln(src))
  ln_kernel<0, 1><<<dim3(NROWS / 4), dim3(256), 0, stream>>>(src, g_ffm, b_ffm, lnb);
  gemm2(1, lnb, wb_ffm1, ffm_b1, hbig, NROWS, FF, DM);
  gemmR(1, hbig, wb_ffm2, ffm_b2, src, 0.5f, x1, NROWS, DM, FF);

  // MHA: x2 = x1 + out_proj(attn(ln(x1)))
  ln_kernel<0, 0><<<dim3(NROWS / 4), dim3(256), 0, stream>>>(x1, g_mha, b_mha, lnb);
  gemm128<0, 0><<<dim3((NROWS / 128) * (3 * DM / 128)), dim3(256), 0, stream>>>(
      lnb, wb_in, in_b, nullptr, 0.f, qkvb, NROWS, 3 * DM, DM);
  prep_kernel<<<dim3(1024), dim3(256), 0, stream>>>(qkvb, VTp);
  attn_kernel<<<dim3(512), dim3(512), 0, stream>>>(qkvb, VTp, pos_bf, bias_u, bias_v, obuf);
  gemmR(0, obuf, wb_out, out_b, x1, 1.f, x2, NROWS, DM, DM);

  // conv module: x3 = x2 + pw2(fused[swish(ln(dwconv(glu(pw1(ln(x2))))))])
  ln_kernel<0, 0><<<dim3(NROWS / 4), dim3(256), 0, stream>>>(x2, g_conv, b_conv, lnb);
  gemm128<0, 0><<<dim3((NROWS / 128) * (2 * DM / 128)), dim3(256), 0, stream>>>(
      lnb, wb_pw1, pw1_b, nullptr, 0.f, pw1raw, NROWS, 2 * DM, DM);
  glu_dwconv_kernel<<<dim3(1024), dim3(256), 0, stream>>>(pw1raw, dw_w, dw_b, cng, cnb, convy);
  gemmR(0, convy, wb_pw2, pw2_b, x2, 1.f, x3, NROWS, DM, DM);

  // final FFN: x4 = x3 + ffn(ln(x3))
  ln_kernel<0, 0><<<dim3(NROWS / 4), dim3(256), 0, stream>>>(x3, g_ff, b_ff, lnb);
  gemm2(1, lnb, wb_ff1, ff_b1, hbig, NROWS, FF, DM);
  gemmR(0, hbig, wb_ff2, ff_b2, x3, 1.f, x4, NROWS, DM, FF);

  // final LN -> f32 output
  ln_kernel<1, 0><<<dim3(NROWS / 4), dim3(256), 0, stream>>>(x4, g_fin, b_fin, d_out);

  (void)in_sizes; (void)n_in; (void)out_size; (void)ws_size;
}

// Round 15
// 322.131 us; speedup vs baseline: 1.0613x; 1.0613x over previous
//
#include <hip/hip_runtime.h>

typedef __attribute__((ext_vector_type(8))) short bf16x8;
typedef __attribute__((ext_vector_type(4))) short s16x4;
typedef __attribute__((ext_vector_type(4))) float f32x4;
typedef unsigned int u32;

#define SQ 1024
#define BB 8
#define DM 512
#define NH 8
#define HD 64
#define FF 2048
#define NROWS (SQ*BB)

static __device__ __forceinline__ float b2f(short s) {
  return __uint_as_float(((u32)(unsigned short)s) << 16);
}
static __device__ __forceinline__ short f2b(float f) {
  u32 u = __float_as_uint(f);
  return (short)((u + 0x7FFFu + ((u >> 16) & 1u)) >> 16);
}
// cheap round (non-RNE) for hot inner-loop LDS stores
static __device__ __forceinline__ short f2bt(float f) {
  return (short)((__float_as_uint(f) + 0x8000u) >> 16);
}
static __device__ __forceinline__ float sigm(float x) { return 1.f / (1.f + __expf(-x)); }

static __device__ __forceinline__ f32x4 mfma16(bf16x8 a, bf16x8 b, f32x4 c) {
  return __builtin_amdgcn_mfma_f32_16x16x32_bf16(a, b, c, 0, 0, 0);
}

static __device__ __forceinline__ void gload16(const void* g, void* l) {
  __builtin_amdgcn_global_load_lds(
      (const __attribute__((address_space(1))) void*)g,
      (__attribute__((address_space(3))) void*)l, 16, 0, 0);
}

// XOR swizzle for row-major [*][64 bf16] tiles (128 B row stride)
static __device__ __forceinline__ int swzp(int r, int byteoff) {
  return (r * 128 + byteoff) ^ ((r & 7) << 4);
}

#define WAIT_LGKM() do { \
    asm volatile("s_waitcnt lgkmcnt(0)" ::: "memory"); \
    __builtin_amdgcn_sched_barrier(0); } while (0)
#define WAIT_VM(n) do { \
    asm volatile("s_waitcnt vmcnt(" #n ")" ::: "memory"); \
    __builtin_amdgcn_sched_barrier(0); } while (0)

// ---------------- batched f32 -> bf16 convert (10 segments, 1 launch) ----------------
struct CvtArgs {
  const float* s[10];
  short* d[10];
  int n4[10];
  int cum[10];
};
__global__ __launch_bounds__(256) void cvt_multi(CvtArgs a) {
  int bid = blockIdx.x;
  int seg = 0;
#pragma unroll
  for (int i = 1; i < 10; ++i) if (bid >= a.cum[i]) seg = i;
  int idx = (bid - a.cum[seg]) * 256 + threadIdx.x;
  if (idx >= a.n4[seg]) return;
  float4 v = ((const float4*)a.s[seg])[idx];
  s16x4 r = { f2b(v.x), f2b(v.y), f2b(v.z), f2b(v.w) };
  ((s16x4*)a.d[seg])[idx] = r;
}

// ---------------- row LayerNorm, D=512, one wave per row ----------------
// MODE 0: bf16 out; 1: f32 out.  INF32: input dtype.
template<int MODE, int INF32>
__global__ __launch_bounds__(256) void ln_kernel(const void* __restrict__ xin,
                                                 const float* __restrict__ gam,
                                                 const float* __restrict__ bet,
                                                 void* __restrict__ out) {
  int w = threadIdx.x >> 6, lane = threadIdx.x & 63;
  int row = (blockIdx.x << 2) + w;
  float v[8];
  if (INF32) {
    const float* xr = (const float*)xin + (size_t)row * DM + lane * 8;
    float4 a = *(const float4*)xr;
    float4 c = *(const float4*)(xr + 4);
    v[0]=a.x; v[1]=a.y; v[2]=a.z; v[3]=a.w; v[4]=c.x; v[5]=c.y; v[6]=c.z; v[7]=c.w;
  } else {
    bf16x8 x8 = *(const bf16x8*)((const short*)xin + (size_t)row * DM + lane * 8);
#pragma unroll
    for (int e = 0; e < 8; ++e) v[e] = b2f(x8[e]);
  }
  float s = 0.f, q = 0.f;
#pragma unroll
  for (int e = 0; e < 8; ++e) { s += v[e]; q += v[e] * v[e]; }
#pragma unroll
  for (int m = 1; m < 64; m <<= 1) { s += __shfl_xor(s, m); q += __shfl_xor(q, m); }
  float mean = s * (1.f / DM);
  float rstd = rsqrtf(q * (1.f / DM) - mean * mean + 1e-5f);
  int col = lane * 8;
  if (MODE == 1) {
    float* o = (float*)out + (size_t)row * DM + col;
    float y[8];
#pragma unroll
    for (int e = 0; e < 8; ++e) y[e] = (v[e] - mean) * rstd * gam[col + e] + bet[col + e];
    *(float4*)o = make_float4(y[0], y[1], y[2], y[3]);
    *(float4*)(o + 4) = make_float4(y[4], y[5], y[6], y[7]);
  } else {
    bf16x8 r;
#pragma unroll
    for (int e = 0; e < 8; ++e) {
      float y = (v[e] - mean) * rstd * gam[col + e] + bet[col + e];
      r[e] = f2b(y);
    }
    *(bf16x8*)((short*)out + (size_t)row * DM + col) = r;
  }
}

// ---------------- 256x256 GEMM, BK=32, ring-3, counted vmcnt, st_16x32 swizzle ----------------
template<int EPI>
__global__ __launch_bounds__(512, 2) void gemm256(const short* __restrict__ A,
                                                  const short* __restrict__ W,
                                                  const float* __restrict__ bias,
                                                  short* __restrict__ out,
                                                  int M, int N, int K) {
  __shared__ __align__(16) short lds[3 * 16384];
  int nb = N >> 8;
  int nwg = gridDim.x, bid = blockIdx.x;
  int bid2 = ((nwg & 7) == 0) ? ((bid & 7) * (nwg >> 3) + (bid >> 3)) : bid;
  int bm = bid2 / nb, bn = bid2 % nb;
  int m0 = bm << 8, n0 = bn << 8;
  int tid = threadIdx.x, w = tid >> 6, lane = tid & 63;
  int wm = w >> 2, wn = w & 3;
  int l15 = lane & 15, l4 = lane >> 4;
  int srow = lane >> 2;
  int slog = (lane & 3) ^ (((lane >> 5) & 1) << 1);
  int scol = slog << 3;

  const short* gsrc = (w < 4) ? (A + (size_t)(m0 + w * 64 + srow) * K + scol)
                              : (W + (size_t)(n0 + (w - 4) * 64 + srow) * K + scol);

  f32x4 acc[8][4];
#pragma unroll
  for (int i = 0; i < 8; ++i)
#pragma unroll
    for (int j = 0; j < 4; ++j) acc[i][j] = (f32x4){0.f, 0.f, 0.f, 0.f};

  auto stage2 = [&](int u, int kt, int q0) {
#pragma unroll
    for (int q = q0; q < q0 + 2; ++q)
      gload16(gsrc + (size_t)(q * 16) * K + kt,
              (char*)lds + u * 32768 + (w * 4 + q) * 1024);
  };
  auto rdA = [&](int u, int mf) -> bf16x8 {
    int ps = l4 ^ (((l15 >> 3) & 1) << 1);
    return *(const bf16x8*)((char*)lds + u * 32768 + (wm * 8 + mf) * 1024 + l15 * 64 + ps * 16);
  };
  auto rdB = [&](int u, int nf) -> bf16x8 {
    int ps = l4 ^ (((l15 >> 3) & 1) << 1);
    return *(const bf16x8*)((char*)lds + u * 32768 + 16384 + (wn * 4 + nf) * 1024 + l15 * 64 + ps * 16);
  };

  int nt = K >> 5;
  stage2(0, 0, 0); stage2(0, 0, 2);
  stage2(1, 32, 0); stage2(1, 32, 2);
  WAIT_VM(4);
  __builtin_amdgcn_s_barrier();

  int u = 0;
  for (int t = 0; t < nt; ++t) {
    int kt2 = (t + 2) << 5;
    int us = u + 2; if (us >= 3) us -= 3;
    bool st = (t + 2) < nt;
    bf16x8 afrag[4], bfrag[4];
#pragma unroll
    for (int nf = 0; nf < 4; ++nf) bfrag[nf] = rdB(u, nf);
#pragma unroll
    for (int mf = 0; mf < 4; ++mf) afrag[mf] = rdA(u, mf);
    if (st) stage2(us, kt2, 0);
    __builtin_amdgcn_s_barrier();
    WAIT_LGKM();
    __builtin_amdgcn_s_setprio(1);
#pragma unroll
    for (int mf = 0; mf < 4; ++mf)
#pragma unroll
      for (int nf = 0; nf < 4; ++nf)
        acc[mf][nf] = mfma16(afrag[mf], bfrag[nf], acc[mf][nf]);
    __builtin_amdgcn_s_setprio(0);
    __builtin_amdgcn_s_barrier();
#pragma unroll
    for (int mf = 0; mf < 4; ++mf) afrag[mf] = rdA(u, mf + 4);
    if (st) stage2(us, kt2, 2);
    __builtin_amdgcn_s_barrier();
    WAIT_LGKM();
    __builtin_amdgcn_s_setprio(1);
#pragma unroll
    for (int mf = 0; mf < 4; ++mf)
#pragma unroll
      for (int nf = 0; nf < 4; ++nf)
        acc[mf + 4][nf] = mfma16(afrag[mf], bfrag[nf], acc[mf + 4][nf]);
    __builtin_amdgcn_s_setprio(0);
    if (t < nt - 1) {
      if (st) { WAIT_VM(4); } else { WAIT_VM(0); }
    }
    __builtin_amdgcn_s_barrier();
    ++u; if (u >= 3) u -= 3;
  }

#pragma unroll
  for (int nf = 0; nf < 4; ++nf) {
    int col = n0 + wn * 64 + nf * 16 + l15;
    float bv = bias[col];
#pragma unroll
    for (int mf = 0; mf < 8; ++mf) {
#pragma unroll
      for (int r4 = 0; r4 < 4; ++r4) {
        int row = m0 + wm * 128 + mf * 16 + l4 * 4 + r4;
        float v = acc[mf][nf][r4] + bv;
        if (EPI == 1) v = v * sigm(v);
        out[(size_t)row * N + col] = f2b(v);
      }
    }
  }
}

// ---------------- 128x128 GEMM: ring-3, counted vmcnt, 1 barrier/iter ----------------
// EPI 0: +bias -> bf16 ; 1: swish(+bias) -> bf16 ; 2: res + alpha*(acc+bias) -> bf16 ;
// 3: plain -> bf16.  RESF32: residual dtype.
template<int EPI, int RESF32>
__global__ __launch_bounds__(256, 3) void gemm128(const short* __restrict__ A,
                                                  const short* __restrict__ W,
                                                  const float* __restrict__ bias,
                                                  const void* __restrict__ res,
                                                  float alpha, short* __restrict__ out,
                                                  int M, int N, int K) {
  __shared__ __align__(16) short lds[3 * 8192];
  int nb = N >> 7;
  int nwg = gridDim.x, bid = blockIdx.x;
  int bid2 = ((nwg & 7) == 0) ? ((bid & 7) * (nwg >> 3) + (bid >> 3)) : bid;
  int bm = bid2 / nb, bn = bid2 % nb;
  int m0 = bm << 7, n0 = bn << 7;
  int tid = threadIdx.x, w = tid >> 6, lane = tid & 63;
  int wm = w >> 1, wn = w & 1;
  int l15 = lane & 15, l4 = lane >> 4;
  int srow = lane >> 2;
  int slog = (lane & 3) ^ (((lane >> 5) & 1) << 1);
  int scol = slog << 3;

  const short* gsrc = (w < 2) ? (A + (size_t)(m0 + w * 64 + srow) * K + scol)
                              : (W + (size_t)(n0 + (w - 2) * 64 + srow) * K + scol);
  int ldsbase = w * 4096;

  f32x4 acc[4][4];
#pragma unroll
  for (int i = 0; i < 4; ++i)
#pragma unroll
    for (int j = 0; j < 4; ++j) acc[i][j] = (f32x4){0.f, 0.f, 0.f, 0.f};

  auto stage = [&](int u, int kt) {
#pragma unroll
    for (int q = 0; q < 4; ++q)
      gload16(gsrc + (size_t)(q * 16) * K + kt,
              (char*)lds + u * 16384 + ldsbase + q * 1024);
  };
  auto rdA = [&](int u, int mf) -> bf16x8 {
    int ps = l4 ^ (((l15 >> 3) & 1) << 1);
    return *(const bf16x8*)((char*)lds + u * 16384 + (wm * 4 + mf) * 1024 + l15 * 64 + ps * 16);
  };
  auto rdB = [&](int u, int nf) -> bf16x8 {
    int ps = l4 ^ (((l15 >> 3) & 1) << 1);
    return *(const bf16x8*)((char*)lds + u * 16384 + 8192 + (wn * 4 + nf) * 1024 + l15 * 64 + ps * 16);
  };

  int nt = K >> 5;
  stage(0, 0);
  stage(1, 32);
  WAIT_VM(4);
  __builtin_amdgcn_s_barrier();

  int u = 0;
  for (int t = 0; t < nt; ++t) {
    int us = u + 2; if (us >= 3) us -= 3;
    bool st = (t + 2) < nt;
    bf16x8 afrag[4], bfrag[4];
#pragma unroll
    for (int mf = 0; mf < 4; ++mf) afrag[mf] = rdA(u, mf);
#pragma unroll
    for (int nf = 0; nf < 4; ++nf) bfrag[nf] = rdB(u, nf);
    if (st) stage(us, (t + 2) << 5);
    WAIT_LGKM();
    __builtin_amdgcn_s_setprio(1);
#pragma unroll
    for (int mf = 0; mf < 4; ++mf)
#pragma unroll
      for (int nf = 0; nf < 4; ++nf)
        acc[mf][nf] = mfma16(afrag[mf], bfrag[nf], acc[mf][nf]);
    __builtin_amdgcn_s_setprio(0);
    if (t < nt - 1) {
      if (st) { WAIT_VM(4); } else { WAIT_VM(0); }
    }
    __builtin_amdgcn_s_barrier();
    ++u; if (u >= 3) u -= 3;
  }

#pragma unroll
  for (int mf = 0; mf < 4; ++mf) {
#pragma unroll
    for (int nf = 0; nf < 4; ++nf) {
      int col = n0 + wn * 64 + nf * 16 + l15;
      float bv = (EPI == 3) ? 0.f : bias[col];
#pragma unroll
      for (int r4 = 0; r4 < 4; ++r4) {
        int row = m0 + wm * 64 + mf * 16 + l4 * 4 + r4;
        size_t idx = (size_t)row * N + col;
        float v = acc[mf][nf][r4] + bv;
        if (EPI == 0 || EPI == 3) {
          out[idx] = f2b(v);
        } else if (EPI == 1) {
          out[idx] = f2b(v * sigm(v));
        } else {
          float rv = RESF32 ? ((const float*)res)[idx] : b2f(((const short*)res)[idx]);
          out[idx] = f2b(rv + alpha * v);
        }
      }
    }
  }
}

// ---------------- V-transpose prep: qkv V section -> VT [bh][d][s] ----------------
__global__ __launch_bounds__(256) void prep_kernel(const short* __restrict__ qkv,
                                                   short* __restrict__ VTp) {
  __shared__ short ldsv[64 * 66];
  int tid = threadIdx.x;
  int st = blockIdx.x & 15, bh = blockIdx.x >> 4;
  int b = bh >> 3, h = bh & 7;
  int s0 = st << 6;
#pragma unroll
  for (int pass = 0; pass < 2; ++pass) {
    int r = pass * 32 + (tid >> 3), c = tid & 7;
    int s = s0 + r;
    bf16x8 v8 = *(const bf16x8*)(qkv + (size_t)(s * BB + b) * 1536 + 1024 + h * 64 + c * 8);
    *(bf16x8*)(ldsv + r * 66 + c * 8) = v8;
  }
  __syncthreads();
#pragma unroll
  for (int pass = 0; pass < 2; ++pass) {
    int d = pass * 32 + (tid >> 3), sc = tid & 7;
    bf16x8 o;
#pragma unroll
    for (int u = 0; u < 8; ++u) o[u] = ldsv[(sc * 8 + u) * 66 + d];
    *(bf16x8*)(VTp + ((size_t)bh * 64 + d) * SQ + s0 + sc * 8) = o;
  }
}

// ---------------- fused rel-pos flash attention ----------------
// grid = 8(it) * 64(bh) [XCD-local]; block 512 (8 waves)
__global__ __launch_bounds__(512, 4) void attn_kernel(const short* __restrict__ qkv,
                                                      const short* __restrict__ VTp,
                                                      const short* __restrict__ posb,
                                                      const float* __restrict__ bias_u,
                                                      const float* __restrict__ bias_v,
                                                      short* __restrict__ obuf) {
  __shared__ __align__(16) char smem[78848];
  char* lds_k   = smem;            // 2 x [64][64] bf16 swizzled (16KB)
  char* lds_vt  = smem + 16384;    // [64 d][64 j] (8KB)
  char* lds_pos = smem + 24576;    // 4 segs x [64][64] (32KB), circular
  char* lds_ew  = smem + 57344;    // 8 waves x 2688B; e band [16 q][84 n]; P overlaps

  int tid = threadIdx.x, w = tid >> 6, lane = tid & 63;
  int l15 = lane & 15, l4 = lane >> 4;
  int it = blockIdx.x >> 6, bh = blockIdx.x & 63;
  int b = bh >> 3, h = bh & 7;
  int i0 = it << 7;
  char* ewb = lds_ew + w * 2688;

  const size_t hoffB = (size_t)bh * SQ * 128;

  const float SC2 = 0.125f * 1.44269504f;
  int fr = i0 + w * 16 + l15;
  const short* qrow = qkv + (size_t)(fr * BB + b) * 1536 + h * 64;
  bf16x8 qu_f[2], qv_f[2];
#pragma unroll
  for (int ks = 0; ks < 2; ++ks) {
    bf16x8 qraw = *(const bf16x8*)(qrow + ks * 32 + l4 * 8);
#pragma unroll
    for (int e = 0; e < 8; ++e) {
      float qf = b2f(qraw[e]);
      int d = h * 64 + ks * 32 + l4 * 8 + e;
      qu_f[ks][e] = f2b((qf + bias_u[d]) * SC2);
      qv_f[ks][e] = f2b((qf + bias_v[d]) * SC2);
    }
  }

  float m_run = -1e30f, l_run = 0.f;
  f32x4 o_acc[4];
#pragma unroll
  for (int dt = 0; dt < 4; ++dt) o_acc[dt] = (f32x4){0.f, 0.f, 0.f, 0.f};

  int prbase = 112 - 16 * w;
  int lnq = lane >> 3, lnr = lane & 7;
  int r8 = w * 8 + lnq;
  int byt = (lnr * 16) ^ ((r8 & 7) << 4);
  int nbase = 896 - i0;

  auto stageK = [&](int t1) {
    int j = (t1 << 6) + r8;
    gload16((const char*)qkv + (size_t)(j * BB + b) * 3072 + 1024 + h * 128 + byt,
            lds_k + (t1 & 1) * 8192 + w * 1024);
  };
  auto stageVT = [&](int t1) {
    gload16((const char*)VTp + hoffB + (size_t)r8 * 2048 + (size_t)(t1 << 7) + byt,
            lds_vt + w * 1024);
  };
  auto stagePosSeg = [&](int gbase, int pseg) {
    gload16((const char*)posb + (size_t)(gbase + r8) * 1024 + h * 128 + byt,
            lds_pos + pseg * 8192 + w * 1024);
  };

  stagePosSeg(nbase, 0);
  stagePosSeg(nbase + 64, 1);
  stagePosSeg(nbase + 128, 2);
  stageK(0);
  WAIT_VM(0);

  for (int t = 0; t < 16; ++t) {
    int cur = t & 1;
    __builtin_amdgcn_s_barrier();
    stageVT(t);

    f32x4 acs[4];
    __builtin_amdgcn_s_setprio(1);
#pragma unroll
    for (int kt = 0; kt < 4; ++kt) {
      f32x4 z = (f32x4){0.f, 0.f, 0.f, 0.f};
      bf16x8 kb0 = *(const bf16x8*)(lds_k + cur * 8192 + swzp(kt * 16 + l15, l4 * 16));
      bf16x8 kb1 = *(const bf16x8*)(lds_k + cur * 8192 + swzp(kt * 16 + l15, 64 + l4 * 16));
      z = mfma16(kb0, qu_f[0], z);
      z = mfma16(kb1, qu_f[1], z);
      acs[kt] = z;
    }
    __builtin_amdgcn_s_setprio(0);
#pragma unroll
    for (int pt = 0; pt < 5; ++pt) {
      f32x4 z = (f32x4){0.f, 0.f, 0.f, 0.f};
      int pr = prbase + pt * 16 + l15;
      char* pbase = lds_pos + (((t + (pr >> 6)) & 3) * 8192);
      bf16x8 pb0 = *(const bf16x8*)(pbase + swzp(pr & 63, l4 * 16));
      bf16x8 pb1 = *(const bf16x8*)(pbase + swzp(pr & 63, 64 + l4 * 16));
      __builtin_amdgcn_s_setprio(1);
      z = mfma16(pb0, qv_f[0], z);
      z = mfma16(pb1, qv_f[1], z);
      __builtin_amdgcn_s_setprio(0);
      s16x4 ek;
#pragma unroll
      for (int r = 0; r < 4; ++r) ek[r] = f2bt(z[r]);
      *(s16x4*)(ewb + (l15 * 84 + pt * 16 + l4 * 4) * 2) = ek;
    }

    bool pf = (t + 1) < 16;
    if (pf) {
      stageK(t + 1);
      stagePosSeg(nbase + (t << 6) + 192, (t + 3) & 3);
    }

    WAIT_LGKM();

    float sv[4][4];
#pragma unroll
    for (int kt = 0; kt < 4; ++kt) {
#pragma unroll
      for (int r = 0; r < 4; ++r) {
        int n = 15 - l15 + kt * 16 + l4 * 4 + r;
        float ev = b2f(*(const short*)(ewb + (l15 * 84 + n) * 2));
        sv[kt][r] = acs[kt][r] + ev;
      }
    }
    float mk[4];
#pragma unroll
    for (int kt = 0; kt < 4; ++kt)
      mk[kt] = fmaxf(fmaxf(sv[kt][0], sv[kt][1]), fmaxf(sv[kt][2], sv[kt][3]));
    float mt = fmaxf(fmaxf(mk[0], mk[1]), fmaxf(mk[2], mk[3]));

    if (!__all(mt <= m_run + 11.5415604f)) {
      float mr = fmaxf(mt, __shfl_xor(mt, 16));
      mr = fmaxf(mr, __shfl_xor(mr, 32));
      float mn = fmaxf(m_run, mr);
      float fac = exp2f(m_run - mn);
      m_run = mn;
      l_run *= fac;
      float fb[4];
#pragma unroll
      for (int r4 = 0; r4 < 4; ++r4) fb[r4] = __shfl(fac, (l4 << 2) + r4);
#pragma unroll
      for (int dt = 0; dt < 4; ++dt)
#pragma unroll
        for (int r4 = 0; r4 < 4; ++r4) o_acc[dt][r4] *= fb[r4];
    }
    float lsk[4];
#pragma unroll
    for (int kt = 0; kt < 4; ++kt) {
      s16x4 pk;
      float p[4];
#pragma unroll
      for (int r = 0; r < 4; ++r) {
        p[r] = exp2f(sv[kt][r] - m_run);
        pk[r] = f2bt(p[r]);
      }
      lsk[kt] = (p[0] + p[1]) + (p[2] + p[3]);
      *(s16x4*)(ewb + l15 * 128 + ((kt * 32 + l4 * 8) ^ ((l15 & 7) << 4))) = pk;
    }
    l_run += (lsk[0] + lsk[1]) + (lsk[2] + lsk[3]);

    if (pf) { WAIT_VM(2); } else { WAIT_VM(0); }
    WAIT_LGKM();
    __builtin_amdgcn_s_barrier();

    bf16x8 pa[2];
#pragma unroll
    for (int ks = 0; ks < 2; ++ks)
      pa[ks] = *(const bf16x8*)(ewb + swzp(l15, ks * 64 + l4 * 16));
    __builtin_amdgcn_s_setprio(1);
#pragma unroll
    for (int dt = 0; dt < 4; ++dt) {
      bf16x8 vb0 = *(const bf16x8*)(lds_vt + swzp(dt * 16 + l15, l4 * 16));
      bf16x8 vb1 = *(const bf16x8*)(lds_vt + swzp(dt * 16 + l15, 64 + l4 * 16));
      o_acc[dt] = mfma16(pa[0], vb0, o_acc[dt]);
      o_acc[dt] = mfma16(pa[1], vb1, o_acc[dt]);
    }
    __builtin_amdgcn_s_setprio(0);

    WAIT_VM(0);
  }

  float lt = l_run + __shfl_xor(l_run, 16);
  lt += __shfl_xor(lt, 32);
  float lb[4];
#pragma unroll
  for (int r4 = 0; r4 < 4; ++r4) lb[r4] = __shfl(lt, (l4 << 2) + r4);
#pragma unroll
  for (int dt = 0; dt < 4; ++dt) {
#pragma unroll
    for (int r4 = 0; r4 < 4; ++r4) {
      int i = i0 + w * 16 + l4 * 4 + r4;
      int d = dt * 16 + l15;
      float val = o_acc[dt][r4] / lb[r4];
      obuf[(size_t)(i * BB + b) * DM + h * 64 + d] = f2b(val);
    }
  }
}

// ---------------- GLU + depthwise conv (K=31) + fused LayerNorm + swish -> bf16 ----------------
__global__ __launch_bounds__(256) void glu_dwconv_kernel(const short* __restrict__ pw1,
                                                         const float* __restrict__ dww,
                                                         const float* __restrict__ dwb,
                                                         const float* __restrict__ cg,
                                                         const float* __restrict__ cb,
                                                         short* __restrict__ outbf) {
  __shared__ short glu[38 * 512];
  __shared__ float red[8][4][2];
  int tid = threadIdx.x;
  int b = blockIdx.x & 7;
  int s0 = (blockIdx.x >> 3) << 3;
  for (int idx = tid; idx < 38 * 64; idx += 256) {
    int r = idx >> 6, c8 = idx & 63;
    int s = s0 - 15 + r;
    bf16x8 res;
    if (s >= 0 && s < SQ) {
      const short* row = pw1 + (size_t)(s * BB + b) * 1024;
      bf16x8 a8 = *(const bf16x8*)(row + c8 * 8);
      bf16x8 g8 = *(const bf16x8*)(row + 512 + c8 * 8);
#pragma unroll
      for (int e = 0; e < 8; ++e) res[e] = f2b(b2f(a8[e]) * sigm(b2f(g8[e])));
    } else {
#pragma unroll
      for (int e = 0; e < 8; ++e) res[e] = 0;
    }
    *(bf16x8*)(glu + r * 512 + c8 * 8) = res;
  }
  __syncthreads();

  float a0[8], a1[8];
  {
    float wreg[31];
#pragma unroll
    for (int k = 0; k < 31; ++k) wreg[k] = dww[tid * 31 + k];
    float bb = dwb[tid];
    for (int ri = 0; ri < 8; ++ri) {
      float acc = bb;
#pragma unroll
      for (int k = 0; k < 31; ++k)
        acc += wreg[k] * b2f(glu[(ri + k) * 512 + tid]);
      a0[ri] = acc;
    }
  }
  {
    int d = tid + 256;
    float wreg[31];
#pragma unroll
    for (int k = 0; k < 31; ++k) wreg[k] = dww[d * 31 + k];
    float bb = dwb[d];
    for (int ri = 0; ri < 8; ++ri) {
      float acc = bb;
#pragma unroll
      for (int k = 0; k < 31; ++k)
        acc += wreg[k] * b2f(glu[(ri + k) * 512 + d]);
      a1[ri] = acc;
    }
  }

  int w = tid >> 6, lane = tid & 63;
#pragma unroll
  for (int ri = 0; ri < 8; ++ri) {
    float sp = a0[ri] + a1[ri];
    float qp = a0[ri] * a0[ri] + a1[ri] * a1[ri];
#pragma unroll
    for (int m = 1; m < 64; m <<= 1) { sp += __shfl_xor(sp, m); qp += __shfl_xor(qp, m); }
    if (lane == 0) { red[ri][w][0] = sp; red[ri][w][1] = qp; }
  }
  __syncthreads();
  float g0 = cg[tid], b0 = cb[tid], g1 = cg[tid + 256], b1 = cb[tid + 256];
#pragma unroll
  for (int ri = 0; ri < 8; ++ri) {
    float s = red[ri][0][0] + red[ri][1][0] + red[ri][2][0] + red[ri][3][0];
    float q = red[ri][0][1] + red[ri][1][1] + red[ri][2][1] + red[ri][3][1];
    float mean = s * (1.f / DM);
    float rstd = rsqrtf(q * (1.f / DM) - mean * mean + 1e-5f);
    float y0 = (a0[ri] - mean) * rstd * g0 + b0;
    float y1 = (a1[ri] - mean) * rstd * g1 + b1;
    y0 = y0 * sigm(y0);
    y1 = y1 * sigm(y1);
    size_t base = (size_t)((s0 + ri) * BB + b) * 512;
    outbf[base + tid] = f2b(y0);
    outbf[base + tid + 256] = f2b(y1);
  }
}

// ---------------- host ----------------
extern "C" void kernel_launch(void* const* d_in, const int* in_sizes, int n_in,
                              void* d_out, int out_size, void* d_ws, size_t ws_size,
                              hipStream_t stream) {
  const float* src    = (const float*)d_in[0];
  const float* pose   = (const float*)d_in[1];
  const float* ffm_w1 = (const float*)d_in[2];
  const float* ffm_b1 = (const float*)d_in[3];
  const float* ffm_w2 = (const float*)d_in[4];
  const float* ffm_b2 = (const float*)d_in[5];
  const float* in_w   = (const float*)d_in[6];
  const float* in_b   = (const float*)d_in[7];
  const float* out_w  = (const float*)d_in[8];
  const float* out_b  = (const float*)d_in[9];
  const float* pos_w  = (const float*)d_in[10];
  const float* bias_u = (const float*)d_in[11];
  const float* bias_v = (const float*)d_in[12];
  const float* pw1_w  = (const float*)d_in[13];
  const float* pw1_b  = (const float*)d_in[14];
  const float* dw_w   = (const float*)d_in[15];
  const float* dw_b   = (const float*)d_in[16];
  const float* cng    = (const float*)d_in[17];
  const float* cnb    = (const float*)d_in[18];
  const float* pw2_w  = (const float*)d_in[19];
  const float* pw2_b  = (const float*)d_in[20];
  const float* ff_w1  = (const float*)d_in[21];
  const float* ff_b1  = (const float*)d_in[22];
  const float* ff_w2  = (const float*)d_in[23];
  const float* ff_b2  = (const float*)d_in[24];
  const float* g_ffm  = (const float*)d_in[25];
  const float* b_ffm  = (const float*)d_in[26];
  const float* g_mha  = (const float*)d_in[27];
  const float* b_mha  = (const float*)d_in[28];
  const float* g_conv = (const float*)d_in[29];
  const float* b_conv = (const float*)d_in[30];
  const float* g_ff   = (const float*)d_in[31];
  const float* b_ff   = (const float*)d_in[32];
  const float* g_fin  = (const float*)d_in[33];
  const float* b_fin  = (const float*)d_in[34];

  char* ws = (char*)d_ws;
  size_t off = 0;
  auto alloc = [&](size_t bytes) -> void* {
    void* p = ws + off;
    off += (bytes + 255) & ~(size_t)255;
    return p;
  };
  short* wb_ffm1 = (short*)alloc((size_t)FF * DM * 2);
  short* wb_ffm2 = (short*)alloc((size_t)DM * FF * 2);
  short* wb_in   = (short*)alloc((size_t)3 * DM * DM * 2);
  short* wb_out  = (short*)alloc((size_t)DM * DM * 2);
  short* wb_pos  = (short*)alloc((size_t)DM * DM * 2);
  short* wb_pw1  = (short*)alloc((size_t)2 * DM * DM * 2);
  short* wb_pw2  = (short*)alloc((size_t)DM * DM * 2);
  short* wb_ff1  = (short*)alloc((size_t)FF * DM * 2);
  short* wb_ff2  = (short*)alloc((size_t)DM * FF * 2);
  short* pos_src = (short*)alloc((size_t)2048 * DM * 2);
  short* pos_bf  = (short*)alloc((size_t)2048 * DM * 2);
  short* lnb     = (short*)alloc((size_t)NROWS * DM * 2);
  short* hbig    = (short*)alloc((size_t)NROWS * FF * 2);
  short* qkvb    = (short*)alloc((size_t)NROWS * 3 * DM * 2);
  short* obuf    = (short*)alloc((size_t)NROWS * DM * 2);
  short* x1      = (short*)alloc((size_t)NROWS * DM * 2);
  short* x2      = (short*)alloc((size_t)NROWS * DM * 2);
  short* pw1raw  = hbig;
  short* convy   = obuf;
  short* x3 = x1;
  short* x4 = x2;
  short* VTp = hbig + (size_t)3 * 4194304;

  CvtArgs ca;
  const float* srcs[10] = {ffm_w1, ffm_w2, in_w, out_w, pos_w, pw1_w, pw2_w, ff_w1, ff_w2, pose};
  short* dsts[10] = {wb_ffm1, wb_ffm2, wb_in, wb_out, wb_pos, wb_pw1, wb_pw2, wb_ff1, wb_ff2, pos_src};
  size_t ns[10] = {(size_t)FF*DM, (size_t)DM*FF, (size_t)3*DM*DM, (size_t)DM*DM, (size_t)DM*DM,
                   (size_t)2*DM*DM, (size_t)DM*DM, (size_t)FF*DM, (size_t)DM*FF, (size_t)2047*DM};
  int cum = 0;
  for (int i = 0; i < 10; ++i) {
    ca.s[i] = srcs[i]; ca.d[i] = dsts[i];
    ca.n4[i] = (int)(ns[i] >> 2);
    ca.cum[i] = cum;
    cum += (ca.n4[i] + 255) / 256;
  }
  cvt_multi<<<dim3(cum), dim3(256), 0, stream>>>(ca);

  auto gemmR = [&](int RESF32, const short* A, const short* W, const float* bias,
                   const void* res, float alpha, short* out, int M, int N, int K) {
    dim3 g((M / 128) * (N / 128)), blk(256);
    if (RESF32) gemm128<2, 1><<<g, blk, 0, stream>>>(A, W, bias, res, alpha, out, M, N, K);
    else        gemm128<2, 0><<<g, blk, 0, stream>>>(A, W, bias, res, alpha, out, M, N, K);
  };
  auto gemm2 = [&](int EPI, const short* A, const short* W, const float* bias,
                   short* out, int M, int N, int K) {
    dim3 g((M / 256) * (N / 256)), blk(512);
    if (EPI == 0) gemm256<0><<<g, blk, 0, stream>>>(A, W, bias, out, M, N, K);
    else          gemm256<1><<<g, blk, 0, stream>>>(A, W, bias, out, M, N, K);
  };

  // positional projection (plain bf16 out): 2048x512x512
  gemm128<3, 0><<<dim3((2048 / 128) * (512 / 128)), dim3(256), 0, stream>>>(
      pos_src, wb_pos, nullptr, nullptr, 0.f, pos_bf, 2048, DM, DM);

  // macaron FFN: x1 = src + 0.5*ffn(ln(src))
  ln_kernel<0, 1><<<dim3(NROWS / 4), dim3(256), 0, stream>>>(src, g_ffm, b_ffm, lnb);
  gemm2(1, lnb, wb_ffm1, ffm_b1, hbig, NROWS, FF, DM);
  gemmR(1, hbig, wb_ffm2, ffm_b2, src, 0.5f, x1, NROWS, DM, FF);

  // MHA: x2 = x1 + out_proj(attn(ln(x1)))
  ln_kernel<0, 0><<<dim3(NROWS / 4), dim3(256), 0, stream>>>(x1, g_mha, b_mha, lnb);
  gemm128<0, 0><<<dim3((NROWS / 128) * (3 * DM / 128)), dim3(256), 0, stream>>>(
      lnb, wb_in, in_b, nullptr, 0.f, qkvb, NROWS, 3 * DM, DM);
  prep_kernel<<<dim3(1024), dim3(256), 0, stream>>>(qkvb, VTp);
  attn_kernel<<<dim3(512), dim3(512), 0, stream>>>(qkvb, VTp, pos_bf, bias_u, bias_v, obuf);
  gemmR(0, obuf, wb_out, out_b, x1, 1.f, x2, NROWS, DM, DM);

  // conv module: x3 = x2 + pw2(fused[swish(ln(dwconv(glu(pw1(ln(x2))))))])
  ln_kernel<0, 0><<<dim3(NROWS / 4), dim3(256), 0, stream>>>(x2, g_conv, b_conv, lnb);
  gemm128<0, 0><<<dim3((NROWS / 128) * (2 * DM / 128)), dim3(256), 0, stream>>>(
      lnb, wb_pw1, pw1_b, nullptr, 0.f, pw1raw, NROWS, 2 * DM, DM);
  glu_dwconv_kernel<<<dim3(1024), dim3(256), 0, stream>>>(pw1raw, dw_w, dw_b, cng, cnb, convy);
  gemmR(0, convy, wb_pw2, pw2_b, x2, 1.f, x3, NROWS, DM, DM);

  // final FFN: x4 = x3 + ffn(ln(x3))
  ln_kernel<0, 0><<<dim3(NROWS / 4), dim3(256), 0, stream>>>(x3, g_ff, b_ff, lnb);
  gemm2(1, lnb, wb_ff1, ff_b1, hbig, NROWS, FF, DM);
  gemmR(0, hbig, wb_ff2, ff_b2, x3, 1.f, x4, NROWS, DM, FF);

  // final LN -> f32 output
  ln_kernel<1, 0><<<dim3(NROWS / 4), dim3(256), 0, stream>>>(x4, g_fin, b_fin, d_out);

  (void)in_sizes; (void)n_in; (void)out_size; (void)ws_size;
}

// Round 16
// 321.279 us; speedup vs baseline: 1.0642x; 1.0027x over previous
//
#include <hip/hip_runtime.h>

typedef __attribute__((ext_vector_type(8))) short bf16x8;
typedef __attribute__((ext_vector_type(4))) short s16x4;
typedef __attribute__((ext_vector_type(4))) float f32x4;
typedef unsigned int u32;

#define SQ 1024
#define BB 8
#define DM 512
#define NH 8
#define HD 64
#define FF 2048
#define NROWS (SQ*BB)

static __device__ __forceinline__ float b2f(short s) {
  return __uint_as_float(((u32)(unsigned short)s) << 16);
}
static __device__ __forceinline__ short f2b(float f) {
  u32 u = __float_as_uint(f);
  return (short)((u + 0x7FFFu + ((u >> 16) & 1u)) >> 16);
}
// cheap round (non-RNE) for hot inner-loop LDS stores
static __device__ __forceinline__ short f2bt(float f) {
  return (short)((__float_as_uint(f) + 0x8000u) >> 16);
}
static __device__ __forceinline__ float sigm(float x) { return 1.f / (1.f + __expf(-x)); }

static __device__ __forceinline__ f32x4 mfma16(bf16x8 a, bf16x8 b, f32x4 c) {
  return __builtin_amdgcn_mfma_f32_16x16x32_bf16(a, b, c, 0, 0, 0);
}

static __device__ __forceinline__ void gload16(const void* g, void* l) {
  __builtin_amdgcn_global_load_lds(
      (const __attribute__((address_space(1))) void*)g,
      (__attribute__((address_space(3))) void*)l, 16, 0, 0);
}

// XOR swizzle for row-major [*][64 bf16] tiles (128 B row stride)
static __device__ __forceinline__ int swzp(int r, int byteoff) {
  return (r * 128 + byteoff) ^ ((r & 7) << 4);
}

#define WAIT_LGKM() do { \
    asm volatile("s_waitcnt lgkmcnt(0)" ::: "memory"); \
    __builtin_amdgcn_sched_barrier(0); } while (0)
#define WAIT_VM(n) do { \
    asm volatile("s_waitcnt vmcnt(" #n ")" ::: "memory"); \
    __builtin_amdgcn_sched_barrier(0); } while (0)

// ---------------- batched f32 -> bf16 convert (10 segments, 1 launch) ----------------
struct CvtArgs {
  const float* s[10];
  short* d[10];
  int n4[10];
  int cum[10];
};
__global__ __launch_bounds__(256) void cvt_multi(CvtArgs a) {
  int bid = blockIdx.x;
  int seg = 0;
#pragma unroll
  for (int i = 1; i < 10; ++i) if (bid >= a.cum[i]) seg = i;
  int idx = (bid - a.cum[seg]) * 256 + threadIdx.x;
  if (idx >= a.n4[seg]) return;
  float4 v = ((const float4*)a.s[seg])[idx];
  s16x4 r = { f2b(v.x), f2b(v.y), f2b(v.z), f2b(v.w) };
  ((s16x4*)a.d[seg])[idx] = r;
}

// ---------------- row LayerNorm, D=512, one wave per row ----------------
// MODE 0: bf16 out; 1: f32 out.  INF32: input dtype.
template<int MODE, int INF32>
__global__ __launch_bounds__(256) void ln_kernel(const void* __restrict__ xin,
                                                 const float* __restrict__ gam,
                                                 const float* __restrict__ bet,
                                                 void* __restrict__ out) {
  int w = threadIdx.x >> 6, lane = threadIdx.x & 63;
  int row = (blockIdx.x << 2) + w;
  float v[8];
  if (INF32) {
    const float* xr = (const float*)xin + (size_t)row * DM + lane * 8;
    float4 a = *(const float4*)xr;
    float4 c = *(const float4*)(xr + 4);
    v[0]=a.x; v[1]=a.y; v[2]=a.z; v[3]=a.w; v[4]=c.x; v[5]=c.y; v[6]=c.z; v[7]=c.w;
  } else {
    bf16x8 x8 = *(const bf16x8*)((const short*)xin + (size_t)row * DM + lane * 8);
#pragma unroll
    for (int e = 0; e < 8; ++e) v[e] = b2f(x8[e]);
  }
  float s = 0.f, q = 0.f;
#pragma unroll
  for (int e = 0; e < 8; ++e) { s += v[e]; q += v[e] * v[e]; }
#pragma unroll
  for (int m = 1; m < 64; m <<= 1) { s += __shfl_xor(s, m); q += __shfl_xor(q, m); }
  float mean = s * (1.f / DM);
  float rstd = rsqrtf(q * (1.f / DM) - mean * mean + 1e-5f);
  int col = lane * 8;
  if (MODE == 1) {
    float* o = (float*)out + (size_t)row * DM + col;
    float y[8];
#pragma unroll
    for (int e = 0; e < 8; ++e) y[e] = (v[e] - mean) * rstd * gam[col + e] + bet[col + e];
    *(float4*)o = make_float4(y[0], y[1], y[2], y[3]);
    *(float4*)(o + 4) = make_float4(y[4], y[5], y[6], y[7]);
  } else {
    bf16x8 r;
#pragma unroll
    for (int e = 0; e < 8; ++e) {
      float y = (v[e] - mean) * rstd * gam[col + e] + bet[col + e];
      r[e] = f2b(y);
    }
    *(bf16x8*)((short*)out + (size_t)row * DM + col) = r;
  }
}

// ---------------- 256x256 GEMM, BK=32, ring-3, counted vmcnt, st_16x32 swizzle ----------------
template<int EPI>
__global__ __launch_bounds__(512, 2) void gemm256(const short* __restrict__ A,
                                                  const short* __restrict__ W,
                                                  const float* __restrict__ bias,
                                                  short* __restrict__ out,
                                                  int M, int N, int K) {
  __shared__ __align__(16) short lds[3 * 16384];
  int nb = N >> 8;
  int nwg = gridDim.x, bid = blockIdx.x;
  int bid2 = ((nwg & 7) == 0) ? ((bid & 7) * (nwg >> 3) + (bid >> 3)) : bid;
  int bm = bid2 / nb, bn = bid2 % nb;
  int m0 = bm << 8, n0 = bn << 8;
  int tid = threadIdx.x, w = tid >> 6, lane = tid & 63;
  int wm = w >> 2, wn = w & 3;
  int l15 = lane & 15, l4 = lane >> 4;
  int srow = lane >> 2;
  int slog = (lane & 3) ^ (((lane >> 5) & 1) << 1);
  int scol = slog << 3;

  const short* gsrc = (w < 4) ? (A + (size_t)(m0 + w * 64 + srow) * K + scol)
                              : (W + (size_t)(n0 + (w - 4) * 64 + srow) * K + scol);

  f32x4 acc[8][4];
#pragma unroll
  for (int i = 0; i < 8; ++i)
#pragma unroll
    for (int j = 0; j < 4; ++j) acc[i][j] = (f32x4){0.f, 0.f, 0.f, 0.f};

  auto stage2 = [&](int u, int kt, int q0) {
#pragma unroll
    for (int q = q0; q < q0 + 2; ++q)
      gload16(gsrc + (size_t)(q * 16) * K + kt,
              (char*)lds + u * 32768 + (w * 4 + q) * 1024);
  };
  auto rdA = [&](int u, int mf) -> bf16x8 {
    int ps = l4 ^ (((l15 >> 3) & 1) << 1);
    return *(const bf16x8*)((char*)lds + u * 32768 + (wm * 8 + mf) * 1024 + l15 * 64 + ps * 16);
  };
  auto rdB = [&](int u, int nf) -> bf16x8 {
    int ps = l4 ^ (((l15 >> 3) & 1) << 1);
    return *(const bf16x8*)((char*)lds + u * 32768 + 16384 + (wn * 4 + nf) * 1024 + l15 * 64 + ps * 16);
  };

  int nt = K >> 5;
  stage2(0, 0, 0); stage2(0, 0, 2);
  stage2(1, 32, 0); stage2(1, 32, 2);
  WAIT_VM(4);
  __builtin_amdgcn_s_barrier();

  int u = 0;
  for (int t = 0; t < nt; ++t) {
    int kt2 = (t + 2) << 5;
    int us = u + 2; if (us >= 3) us -= 3;
    bool st = (t + 2) < nt;
    bf16x8 afrag[4], bfrag[4];
#pragma unroll
    for (int nf = 0; nf < 4; ++nf) bfrag[nf] = rdB(u, nf);
#pragma unroll
    for (int mf = 0; mf < 4; ++mf) afrag[mf] = rdA(u, mf);
    if (st) stage2(us, kt2, 0);
    __builtin_amdgcn_s_barrier();
    WAIT_LGKM();
    __builtin_amdgcn_s_setprio(1);
#pragma unroll
    for (int mf = 0; mf < 4; ++mf)
#pragma unroll
      for (int nf = 0; nf < 4; ++nf)
        acc[mf][nf] = mfma16(afrag[mf], bfrag[nf], acc[mf][nf]);
    __builtin_amdgcn_s_setprio(0);
    __builtin_amdgcn_s_barrier();
#pragma unroll
    for (int mf = 0; mf < 4; ++mf) afrag[mf] = rdA(u, mf + 4);
    if (st) stage2(us, kt2, 2);
    __builtin_amdgcn_s_barrier();
    WAIT_LGKM();
    __builtin_amdgcn_s_setprio(1);
#pragma unroll
    for (int mf = 0; mf < 4; ++mf)
#pragma unroll
      for (int nf = 0; nf < 4; ++nf)
        acc[mf + 4][nf] = mfma16(afrag[mf], bfrag[nf], acc[mf + 4][nf]);
    __builtin_amdgcn_s_setprio(0);
    if (t < nt - 1) {
      if (st) { WAIT_VM(4); } else { WAIT_VM(0); }
    }
    __builtin_amdgcn_s_barrier();
    ++u; if (u >= 3) u -= 3;
  }

#pragma unroll
  for (int nf = 0; nf < 4; ++nf) {
    int col = n0 + wn * 64 + nf * 16 + l15;
    float bv = bias[col];
#pragma unroll
    for (int mf = 0; mf < 8; ++mf) {
#pragma unroll
      for (int r4 = 0; r4 < 4; ++r4) {
        int row = m0 + wm * 128 + mf * 16 + l4 * 4 + r4;
        float v = acc[mf][nf][r4] + bv;
        if (EPI == 1) v = v * sigm(v);
        out[(size_t)row * N + col] = f2b(v);
      }
    }
  }
}

// ---------------- 128x128 GEMM: ring-3, counted vmcnt, 1 barrier/iter ----------------
// EPI 0: +bias -> bf16 ; 1: swish(+bias) -> bf16 ; 2: res + alpha*(acc+bias) -> bf16 ;
// 3: plain -> bf16.  RESF32: residual dtype.
template<int EPI, int RESF32>
__global__ __launch_bounds__(256, 3) void gemm128(const short* __restrict__ A,
                                                  const short* __restrict__ W,
                                                  const float* __restrict__ bias,
                                                  const void* __restrict__ res,
                                                  float alpha, short* __restrict__ out,
                                                  int M, int N, int K) {
  __shared__ __align__(16) short lds[3 * 8192];
  int nb = N >> 7;
  int nwg = gridDim.x, bid = blockIdx.x;
  int bid2 = ((nwg & 7) == 0) ? ((bid & 7) * (nwg >> 3) + (bid >> 3)) : bid;
  int bm = bid2 / nb, bn = bid2 % nb;
  int m0 = bm << 7, n0 = bn << 7;
  int tid = threadIdx.x, w = tid >> 6, lane = tid & 63;
  int wm = w >> 1, wn = w & 1;
  int l15 = lane & 15, l4 = lane >> 4;
  int srow = lane >> 2;
  int slog = (lane & 3) ^ (((lane >> 5) & 1) << 1);
  int scol = slog << 3;

  const short* gsrc = (w < 2) ? (A + (size_t)(m0 + w * 64 + srow) * K + scol)
                              : (W + (size_t)(n0 + (w - 2) * 64 + srow) * K + scol);
  int ldsbase = w * 4096;

  f32x4 acc[4][4];
#pragma unroll
  for (int i = 0; i < 4; ++i)
#pragma unroll
    for (int j = 0; j < 4; ++j) acc[i][j] = (f32x4){0.f, 0.f, 0.f, 0.f};

  auto stage = [&](int u, int kt) {
#pragma unroll
    for (int q = 0; q < 4; ++q)
      gload16(gsrc + (size_t)(q * 16) * K + kt,
              (char*)lds + u * 16384 + ldsbase + q * 1024);
  };
  auto rdA = [&](int u, int mf) -> bf16x8 {
    int ps = l4 ^ (((l15 >> 3) & 1) << 1);
    return *(const bf16x8*)((char*)lds + u * 16384 + (wm * 4 + mf) * 1024 + l15 * 64 + ps * 16);
  };
  auto rdB = [&](int u, int nf) -> bf16x8 {
    int ps = l4 ^ (((l15 >> 3) & 1) << 1);
    return *(const bf16x8*)((char*)lds + u * 16384 + 8192 + (wn * 4 + nf) * 1024 + l15 * 64 + ps * 16);
  };

  int nt = K >> 5;
  stage(0, 0);
  stage(1, 32);
  WAIT_VM(4);
  __builtin_amdgcn_s_barrier();

  int u = 0;
  for (int t = 0; t < nt; ++t) {
    int us = u + 2; if (us >= 3) us -= 3;
    bool st = (t + 2) < nt;
    bf16x8 afrag[4], bfrag[4];
#pragma unroll
    for (int mf = 0; mf < 4; ++mf) afrag[mf] = rdA(u, mf);
#pragma unroll
    for (int nf = 0; nf < 4; ++nf) bfrag[nf] = rdB(u, nf);
    if (st) stage(us, (t + 2) << 5);
    WAIT_LGKM();
    __builtin_amdgcn_s_setprio(1);
#pragma unroll
    for (int mf = 0; mf < 4; ++mf)
#pragma unroll
      for (int nf = 0; nf < 4; ++nf)
        acc[mf][nf] = mfma16(afrag[mf], bfrag[nf], acc[mf][nf]);
    __builtin_amdgcn_s_setprio(0);
    if (t < nt - 1) {
      if (st) { WAIT_VM(4); } else { WAIT_VM(0); }
    }
    __builtin_amdgcn_s_barrier();
    ++u; if (u >= 3) u -= 3;
  }

#pragma unroll
  for (int mf = 0; mf < 4; ++mf) {
#pragma unroll
    for (int nf = 0; nf < 4; ++nf) {
      int col = n0 + wn * 64 + nf * 16 + l15;
      float bv = (EPI == 3) ? 0.f : bias[col];
#pragma unroll
      for (int r4 = 0; r4 < 4; ++r4) {
        int row = m0 + wm * 64 + mf * 16 + l4 * 4 + r4;
        size_t idx = (size_t)row * N + col;
        float v = acc[mf][nf][r4] + bv;
        if (EPI == 0 || EPI == 3) {
          out[idx] = f2b(v);
        } else if (EPI == 1) {
          out[idx] = f2b(v * sigm(v));
        } else {
          float rv = RESF32 ? ((const float*)res)[idx] : b2f(((const short*)res)[idx]);
          out[idx] = f2b(rv + alpha * v);
        }
      }
    }
  }
}

// ---------------- V-transpose prep: qkv V section -> VT [bh][d][s] ----------------
__global__ __launch_bounds__(256) void prep_kernel(const short* __restrict__ qkv,
                                                   short* __restrict__ VTp) {
  __shared__ short ldsv[64 * 66];
  int tid = threadIdx.x;
  int st = blockIdx.x & 15, bh = blockIdx.x >> 4;
  int b = bh >> 3, h = bh & 7;
  int s0 = st << 6;
#pragma unroll
  for (int pass = 0; pass < 2; ++pass) {
    int r = pass * 32 + (tid >> 3), c = tid & 7;
    int s = s0 + r;
    bf16x8 v8 = *(const bf16x8*)(qkv + (size_t)(s * BB + b) * 1536 + 1024 + h * 64 + c * 8);
    *(bf16x8*)(ldsv + r * 66 + c * 8) = v8;
  }
  __syncthreads();
#pragma unroll
  for (int pass = 0; pass < 2; ++pass) {
    int d = pass * 32 + (tid >> 3), sc = tid & 7;
    bf16x8 o;
#pragma unroll
    for (int u = 0; u < 8; ++u) o[u] = ldsv[(sc * 8 + u) * 66 + d];
    *(bf16x8*)(VTp + ((size_t)bh * 64 + d) * SQ + s0 + sc * 8) = o;
  }
}

// ---------------- fused rel-pos flash attention ----------------
// grid = 8(it) * 64(bh) [XCD-local]; block 512 (8 waves)
__global__ __launch_bounds__(512, 4) void attn_kernel(const short* __restrict__ qkv,
                                                      const short* __restrict__ VTp,
                                                      const short* __restrict__ posb,
                                                      const float* __restrict__ bias_u,
                                                      const float* __restrict__ bias_v,
                                                      short* __restrict__ obuf) {
  __shared__ __align__(16) char smem[78848];
  char* lds_k   = smem;            // 2 x [64][64] bf16 swizzled (16KB)
  char* lds_vt  = smem + 16384;    // [64 d][64 j] (8KB)
  char* lds_pos = smem + 24576;    // 4 segs x [64][64] (32KB), circular
  char* lds_ew  = smem + 57344;    // 8 waves x 2688B; e band [16 q][84 n]; P overlaps

  int tid = threadIdx.x, w = tid >> 6, lane = tid & 63;
  int l15 = lane & 15, l4 = lane >> 4;
  int it = blockIdx.x >> 6, bh = blockIdx.x & 63;
  int b = bh >> 3, h = bh & 7;
  int i0 = it << 7;
  char* ewb = lds_ew + w * 2688;

  const size_t hoffB = (size_t)bh * SQ * 128;

  const float SC2 = 0.125f * 1.44269504f;
  int fr = i0 + w * 16 + l15;
  const short* qrow = qkv + (size_t)(fr * BB + b) * 1536 + h * 64;
  bf16x8 qu_f[2], qv_f[2];
#pragma unroll
  for (int ks = 0; ks < 2; ++ks) {
    bf16x8 qraw = *(const bf16x8*)(qrow + ks * 32 + l4 * 8);
#pragma unroll
    for (int e = 0; e < 8; ++e) {
      float qf = b2f(qraw[e]);
      int d = h * 64 + ks * 32 + l4 * 8 + e;
      qu_f[ks][e] = f2b((qf + bias_u[d]) * SC2);
      qv_f[ks][e] = f2b((qf + bias_v[d]) * SC2);
    }
  }

  float m_run = -1e30f, l_run = 0.f;
  f32x4 o_acc[4];
#pragma unroll
  for (int dt = 0; dt < 4; ++dt) o_acc[dt] = (f32x4){0.f, 0.f, 0.f, 0.f};

  int prbase = 112 - 16 * w;
  int lnq = lane >> 3, lnr = lane & 7;
  int r8 = w * 8 + lnq;
  int byt = (lnr * 16) ^ ((r8 & 7) << 4);
  int nbase = 896 - i0;

  auto stageK = [&](int t1) {
    int j = (t1 << 6) + r8;
    gload16((const char*)qkv + (size_t)(j * BB + b) * 3072 + 1024 + h * 128 + byt,
            lds_k + (t1 & 1) * 8192 + w * 1024);
  };
  auto stageVT = [&](int t1) {
    gload16((const char*)VTp + hoffB + (size_t)r8 * 2048 + (size_t)(t1 << 7) + byt,
            lds_vt + w * 1024);
  };
  auto stagePosSeg = [&](int gbase, int pseg) {
    gload16((const char*)posb + (size_t)(gbase + r8) * 1024 + h * 128 + byt,
            lds_pos + pseg * 8192 + w * 1024);
  };

  stagePosSeg(nbase, 0);
  stagePosSeg(nbase + 64, 1);
  stagePosSeg(nbase + 128, 2);
  stageK(0);
  WAIT_VM(0);

  for (int t = 0; t < 16; ++t) {
    int cur = t & 1;
    __builtin_amdgcn_s_barrier();
    stageVT(t);

    f32x4 acs[4];
    __builtin_amdgcn_s_setprio(1);
#pragma unroll
    for (int kt = 0; kt < 4; ++kt) {
      f32x4 z = (f32x4){0.f, 0.f, 0.f, 0.f};
      bf16x8 kb0 = *(const bf16x8*)(lds_k + cur * 8192 + swzp(kt * 16 + l15, l4 * 16));
      bf16x8 kb1 = *(const bf16x8*)(lds_k + cur * 8192 + swzp(kt * 16 + l15, 64 + l4 * 16));
      z = mfma16(kb0, qu_f[0], z);
      z = mfma16(kb1, qu_f[1], z);
      acs[kt] = z;
    }
    __builtin_amdgcn_s_setprio(0);
#pragma unroll
    for (int pt = 0; pt < 5; ++pt) {
      f32x4 z = (f32x4){0.f, 0.f, 0.f, 0.f};
      int pr = prbase + pt * 16 + l15;
      char* pbase = lds_pos + (((t + (pr >> 6)) & 3) * 8192);
      bf16x8 pb0 = *(const bf16x8*)(pbase + swzp(pr & 63, l4 * 16));
      bf16x8 pb1 = *(const bf16x8*)(pbase + swzp(pr & 63, 64 + l4 * 16));
      __builtin_amdgcn_s_setprio(1);
      z = mfma16(pb0, qv_f[0], z);
      z = mfma16(pb1, qv_f[1], z);
      __builtin_amdgcn_s_setprio(0);
      s16x4 ek;
#pragma unroll
      for (int r = 0; r < 4; ++r) ek[r] = f2bt(z[r]);
      *(s16x4*)(ewb + (l15 * 84 + pt * 16 + l4 * 4) * 2) = ek;
    }

    bool pf = (t + 1) < 16;
    if (pf) {
      stageK(t + 1);
      stagePosSeg(nbase + (t << 6) + 192, (t + 3) & 3);
    }

    WAIT_LGKM();

    float sv[4][4];
#pragma unroll
    for (int kt = 0; kt < 4; ++kt) {
#pragma unroll
      for (int r = 0; r < 4; ++r) {
        int n = 15 - l15 + kt * 16 + l4 * 4 + r;
        float ev = b2f(*(const short*)(ewb + (l15 * 84 + n) * 2));
        sv[kt][r] = acs[kt][r] + ev;
      }
    }
    float mk[4];
#pragma unroll
    for (int kt = 0; kt < 4; ++kt)
      mk[kt] = fmaxf(fmaxf(sv[kt][0], sv[kt][1]), fmaxf(sv[kt][2], sv[kt][3]));
    float mt = fmaxf(fmaxf(mk[0], mk[1]), fmaxf(mk[2], mk[3]));

    if (!__all(mt <= m_run + 11.5415604f)) {
      float mr = fmaxf(mt, __shfl_xor(mt, 16));
      mr = fmaxf(mr, __shfl_xor(mr, 32));
      float mn = fmaxf(m_run, mr);
      float fac = exp2f(m_run - mn);
      m_run = mn;
      l_run *= fac;
      float fb[4];
#pragma unroll
      for (int r4 = 0; r4 < 4; ++r4) fb[r4] = __shfl(fac, (l4 << 2) + r4);
#pragma unroll
      for (int dt = 0; dt < 4; ++dt)
#pragma unroll
        for (int r4 = 0; r4 < 4; ++r4) o_acc[dt][r4] *= fb[r4];
    }
    float lsk[4];
#pragma unroll
    for (int kt = 0; kt < 4; ++kt) {
      s16x4 pk;
      float p[4];
#pragma unroll
      for (int r = 0; r < 4; ++r) {
        p[r] = exp2f(sv[kt][r] - m_run);
        pk[r] = f2bt(p[r]);
      }
      lsk[kt] = (p[0] + p[1]) + (p[2] + p[3]);
      *(s16x4*)(ewb + l15 * 128 + ((kt * 32 + l4 * 8) ^ ((l15 & 7) << 4))) = pk;
    }
    l_run += (lsk[0] + lsk[1]) + (lsk[2] + lsk[3]);

    if (pf) { WAIT_VM(2); } else { WAIT_VM(0); }
    WAIT_LGKM();
    __builtin_amdgcn_s_barrier();

    bf16x8 pa[2];
#pragma unroll
    for (int ks = 0; ks < 2; ++ks)
      pa[ks] = *(const bf16x8*)(ewb + swzp(l15, ks * 64 + l4 * 16));
    __builtin_amdgcn_s_setprio(1);
#pragma unroll
    for (int dt = 0; dt < 4; ++dt) {
      bf16x8 vb0 = *(const bf16x8*)(lds_vt + swzp(dt * 16 + l15, l4 * 16));
      bf16x8 vb1 = *(const bf16x8*)(lds_vt + swzp(dt * 16 + l15, 64 + l4 * 16));
      o_acc[dt] = mfma16(pa[0], vb0, o_acc[dt]);
      o_acc[dt] = mfma16(pa[1], vb1, o_acc[dt]);
    }
    __builtin_amdgcn_s_setprio(0);

    WAIT_VM(0);
  }

  float lt = l_run + __shfl_xor(l_run, 16);
  lt += __shfl_xor(lt, 32);
  float lb[4];
#pragma unroll
  for (int r4 = 0; r4 < 4; ++r4) lb[r4] = __shfl(lt, (l4 << 2) + r4);
#pragma unroll
  for (int dt = 0; dt < 4; ++dt) {
#pragma unroll
    for (int r4 = 0; r4 < 4; ++r4) {
      int i = i0 + w * 16 + l4 * 4 + r4;
      int d = dt * 16 + l15;
      float val = o_acc[dt][r4] / lb[r4];
      obuf[(size_t)(i * BB + b) * DM + h * 64 + d] = f2b(val);
    }
  }
}

// ---------------- GLU + depthwise conv (K=31) + fused LayerNorm + swish -> bf16 ----------------
__global__ __launch_bounds__(256) void glu_dwconv_kernel(const short* __restrict__ pw1,
                                                         const float* __restrict__ dww,
                                                         const float* __restrict__ dwb,
                                                         const float* __restrict__ cg,
                                                         const float* __restrict__ cb,
                                                         short* __restrict__ outbf) {
  __shared__ short glu[38 * 512];
  __shared__ float red[8][4][2];
  int tid = threadIdx.x;
  int b = blockIdx.x & 7;
  int s0 = (blockIdx.x >> 3) << 3;
  for (int idx = tid; idx < 38 * 64; idx += 256) {
    int r = idx >> 6, c8 = idx & 63;
    int s = s0 - 15 + r;
    bf16x8 res;
    if (s >= 0 && s < SQ) {
      const short* row = pw1 + (size_t)(s * BB + b) * 1024;
      bf16x8 a8 = *(const bf16x8*)(row + c8 * 8);
      bf16x8 g8 = *(const bf16x8*)(row + 512 + c8 * 8);
#pragma unroll
      for (int e = 0; e < 8; ++e) res[e] = f2b(b2f(a8[e]) * sigm(b2f(g8[e])));
    } else {
#pragma unroll
      for (int e = 0; e < 8; ++e) res[e] = 0;
    }
    *(bf16x8*)(glu + r * 512 + c8 * 8) = res;
  }
  __syncthreads();

  float a0[8], a1[8];
  {
    float wreg[31];
#pragma unroll
    for (int k = 0; k < 31; ++k) wreg[k] = dww[tid * 31 + k];
    float bb = dwb[tid];
    for (int ri = 0; ri < 8; ++ri) {
      float acc = bb;
#pragma unroll
      for (int k = 0; k < 31; ++k)
        acc += wreg[k] * b2f(glu[(ri + k) * 512 + tid]);
      a0[ri] = acc;
    }
  }
  {
    int d = tid + 256;
    float wreg[31];
#pragma unroll
    for (int k = 0; k < 31; ++k) wreg[k] = dww[d * 31 + k];
    float bb = dwb[d];
    for (int ri = 0; ri < 8; ++ri) {
      float acc = bb;
#pragma unroll
      for (int k = 0; k < 31; ++k)
        acc += wreg[k] * b2f(glu[(ri + k) * 512 + d]);
      a1[ri] = acc;
    }
  }

  int w = tid >> 6, lane = tid & 63;
#pragma unroll
  for (int ri = 0; ri < 8; ++ri) {
    float sp = a0[ri] + a1[ri];
    float qp = a0[ri] * a0[ri] + a1[ri] * a1[ri];
#pragma unroll
    for (int m = 1; m < 64; m <<= 1) { sp += __shfl_xor(sp, m); qp += __shfl_xor(qp, m); }
    if (lane == 0) { red[ri][w][0] = sp; red[ri][w][1] = qp; }
  }
  __syncthreads();
  float g0 = cg[tid], b0 = cb[tid], g1 = cg[tid + 256], b1 = cb[tid + 256];
#pragma unroll
  for (int ri = 0; ri < 8; ++ri) {
    float s = red[ri][0][0] + red[ri][1][0] + red[ri][2][0] + red[ri][3][0];
    float q = red[ri][0][1] + red[ri][1][1] + red[ri][2][1] + red[ri][3][1];
    float mean = s * (1.f / DM);
    float rstd = rsqrtf(q * (1.f / DM) - mean * mean + 1e-5f);
    float y0 = (a0[ri] - mean) * rstd * g0 + b0;
    float y1 = (a1[ri] - mean) * rstd * g1 + b1;
    y0 = y0 * sigm(y0);
    y1 = y1 * sigm(y1);
    size_t base = (size_t)((s0 + ri) * BB + b) * 512;
    outbf[base + tid] = f2b(y0);
    outbf[base + tid + 256] = f2b(y1);
  }
}

// ---------------- host ----------------
extern "C" void kernel_launch(void* const* d_in, const int* in_sizes, int n_in,
                              void* d_out, int out_size, void* d_ws, size_t ws_size,
                              hipStream_t stream) {
  const float* src    = (const float*)d_in[0];
  const float* pose   = (const float*)d_in[1];
  const float* ffm_w1 = (const float*)d_in[2];
  const float* ffm_b1 = (const float*)d_in[3];
  const float* ffm_w2 = (const float*)d_in[4];
  const float* ffm_b2 = (const float*)d_in[5];
  const float* in_w   = (const float*)d_in[6];
  const float* in_b   = (const float*)d_in[7];
  const float* out_w  = (const float*)d_in[8];
  const float* out_b  = (const float*)d_in[9];
  const float* pos_w  = (const float*)d_in[10];
  const float* bias_u = (const float*)d_in[11];
  const float* bias_v = (const float*)d_in[12];
  const float* pw1_w  = (const float*)d_in[13];
  const float* pw1_b  = (const float*)d_in[14];
  const float* dw_w   = (const float*)d_in[15];
  const float* dw_b   = (const float*)d_in[16];
  const float* cng    = (const float*)d_in[17];
  const float* cnb    = (const float*)d_in[18];
  const float* pw2_w  = (const float*)d_in[19];
  const float* pw2_b  = (const float*)d_in[20];
  const float* ff_w1  = (const float*)d_in[21];
  const float* ff_b1  = (const float*)d_in[22];
  const float* ff_w2  = (const float*)d_in[23];
  const float* ff_b2  = (const float*)d_in[24];
  const float* g_ffm  = (const float*)d_in[25];
  const float* b_ffm  = (const float*)d_in[26];
  const float* g_mha  = (const float*)d_in[27];
  const float* b_mha  = (const float*)d_in[28];
  const float* g_conv = (const float*)d_in[29];
  const float* b_conv = (const float*)d_in[30];
  const float* g_ff   = (const float*)d_in[31];
  const float* b_ff   = (const float*)d_in[32];
  const float* g_fin  = (const float*)d_in[33];
  const float* b_fin  = (const float*)d_in[34];

  char* ws = (char*)d_ws;
  size_t off = 0;
  auto alloc = [&](size_t bytes) -> void* {
    void* p = ws + off;
    off += (bytes + 255) & ~(size_t)255;
    return p;
  };
  short* wb_ffm1 = (short*)alloc((size_t)FF * DM * 2);
  short* wb_ffm2 = (short*)alloc((size_t)DM * FF * 2);
  short* wb_in   = (short*)alloc((size_t)3 * DM * DM * 2);
  short* wb_out  = (short*)alloc((size_t)DM * DM * 2);
  short* wb_pos  = (short*)alloc((size_t)DM * DM * 2);
  short* wb_pw1  = (short*)alloc((size_t)2 * DM * DM * 2);
  short* wb_pw2  = (short*)alloc((size_t)DM * DM * 2);
  short* wb_ff1  = (short*)alloc((size_t)FF * DM * 2);
  short* wb_ff2  = (short*)alloc((size_t)DM * FF * 2);
  short* pos_src = (short*)alloc((size_t)2048 * DM * 2);
  short* pos_bf  = (short*)alloc((size_t)2048 * DM * 2);
  short* lnb     = (short*)alloc((size_t)NROWS * DM * 2);
  short* hbig    = (short*)alloc((size_t)NROWS * FF * 2);
  short* qkvb    = (short*)alloc((size_t)NROWS * 3 * DM * 2);
  short* obuf    = (short*)alloc((size_t)NROWS * DM * 2);
  short* x1      = (short*)alloc((size_t)NROWS * DM * 2);
  short* x2      = (short*)alloc((size_t)NROWS * DM * 2);
  short* pw1raw  = hbig;
  short* convy   = obuf;
  short* x3 = x1;
  short* x4 = x2;
  short* VTp = hbig + (size_t)3 * 4194304;

  CvtArgs ca;
  const float* srcs[10] = {ffm_w1, ffm_w2, in_w, out_w, pos_w, pw1_w, pw2_w, ff_w1, ff_w2, pose};
  short* dsts[10] = {wb_ffm1, wb_ffm2, wb_in, wb_out, wb_pos, wb_pw1, wb_pw2, wb_ff1, wb_ff2, pos_src};
  size_t ns[10] = {(size_t)FF*DM, (size_t)DM*FF, (size_t)3*DM*DM, (size_t)DM*DM, (size_t)DM*DM,
                   (size_t)2*DM*DM, (size_t)DM*DM, (size_t)FF*DM, (size_t)DM*FF, (size_t)2047*DM};
  int cum = 0;
  for (int i = 0; i < 10; ++i) {
    ca.s[i] = srcs[i]; ca.d[i] = dsts[i];
    ca.n4[i] = (int)(ns[i] >> 2);
    ca.cum[i] = cum;
    cum += (ca.n4[i] + 255) / 256;
  }
  cvt_multi<<<dim3(cum), dim3(256), 0, stream>>>(ca);

  auto gemmR = [&](int RESF32, const short* A, const short* W, const float* bias,
                   const void* res, float alpha, short* out, int M, int N, int K) {
    dim3 g((M / 128) * (N / 128)), blk(256);
    if (RESF32) gemm128<2, 1><<<g, blk, 0, stream>>>(A, W, bias, res, alpha, out, M, N, K);
    else        gemm128<2, 0><<<g, blk, 0, stream>>>(A, W, bias, res, alpha, out, M, N, K);
  };
  auto gemm2 = [&](int EPI, const short* A, const short* W, const float* bias,
                   short* out, int M, int N, int K) {
    dim3 g((M / 256) * (N / 256)), blk(512);
    if (EPI == 0) gemm256<0><<<g, blk, 0, stream>>>(A, W, bias, out, M, N, K);
    else          gemm256<1><<<g, blk, 0, stream>>>(A, W, bias, out, M, N, K);
  };

  // positional projection (plain bf16 out): 2048x512x512
  gemm128<3, 0><<<dim3((2048 / 128) * (512 / 128)), dim3(256), 0, stream>>>(
      pos_src, wb_pos, nullptr, nullptr, 0.f, pos_bf, 2048, DM, DM);

  // macaron FFN: x1 = src + 0.5*ffn(ln(src))
  ln_kernel<0, 1><<<dim3(NROWS / 4), dim3(256), 0, stream>>>(src, g_ffm, b_ffm, lnb);
  gemm2(1, lnb, wb_ffm1, ffm_b1, hbig, NROWS, FF, DM);
  gemmR(1, hbig, wb_ffm2, ffm_b2, src, 0.5f, x1, NROWS, DM, FF);

  // MHA: x2 = x1 + out_proj(attn(ln(x1)))
  ln_kernel<0, 0><<<dim3(NROWS / 4), dim3(256), 0, stream>>>(x1, g_mha, b_mha, lnb);
  gemm128<0, 0><<<dim3((NROWS / 128) * (3 * DM / 128)), dim3(256), 0, stream>>>(
      lnb, wb_in, in_b, nullptr, 0.f, qkvb, NROWS, 3 * DM, DM);
  prep_kernel<<<dim3(1024), dim3(256), 0, stream>>>(qkvb, VTp);
  attn_kernel<<<dim3(512), dim3(512), 0, stream>>>(qkvb, VTp, pos_bf, bias_u, bias_v, obuf);
  gemmR(0, obuf, wb_out, out_b, x1, 1.f, x2, NROWS, DM, DM);

  // conv module: x3 = x2 + pw2(fused[swish(ln(dwconv(glu(pw1(ln(x2))))))])
  ln_kernel<0, 0><<<dim3(NROWS / 4), dim3(256), 0, stream>>>(x2, g_conv, b_conv, lnb);
  gemm128<0, 0><<<dim3((NROWS / 128) * (2 * DM / 128)), dim3(256), 0, stream>>>(
      lnb, wb_pw1, pw1_b, nullptr, 0.f, pw1raw, NROWS, 2 * DM, DM);
  glu_dwconv_kernel<<<dim3(1024), dim3(256), 0, stream>>>(pw1raw, dw_w, dw_b, cng, cnb, convy);
  gemmR(0, convy, wb_pw2, pw2_b, x2, 1.f, x3, NROWS, DM, DM);

  // final FFN: x4 = x3 + ffn(ln(x3))
  ln_kernel<0, 0><<<dim3(NROWS / 4), dim3(256), 0, stream>>>(x3, g_ff, b_ff, lnb);
  gemm2(1, lnb, wb_ff1, ff_b1, hbig, NROWS, FF, DM);
  gemmR(0, hbig, wb_ff2, ff_b2, x3, 1.f, x4, NROWS, DM, FF);

  // final LN -> f32 output
  ln_kernel<1, 0><<<dim3(NROWS / 4), dim3(256), 0, stream>>>(x4, g_fin, b_fin, d_out);

  (void)in_sizes; (void)n_in; (void)out_size; (void)ws_size;
}